// Round 13
// baseline (574.297 us; speedup 1.0000x reference)
//
#include <hip/hip_runtime.h>
#include <math.h>

static constexpr int BATCH = 4096;
static constexpr int NVIS  = 1024;
static constexpr int NHID  = 4096;
static constexpr int NCOND = 512;

typedef __attribute__((ext_vector_type(8))) short bf16x8;
typedef __attribute__((ext_vector_type(4))) float f32x4;
typedef __attribute__((ext_vector_type(4))) int   i32x4;

static constexpr unsigned HCAP = 131072;
static constexpr unsigned RCAP = 256;
static constexpr size_t MB = 1u << 20;

// ---------------- ws layout (proven) ----------------
static constexpr size_t F_WT0   = 0;                 // W^T bf16 planes (dead after k1)
static constexpr size_t F_WT1   = F_WT0  + 8*MB;
static constexpr size_t F_BMT0  = F_WT1  + 8*MB;
static constexpr size_t F_BMT1  = F_BMT0 + 4*MB;
static constexpr size_t F_AT0   = F_BMT1 + 4*MB;
static constexpr size_t F_AT1   = F_AT0  + 1*MB;
static constexpr size_t F_V0    = F_AT1  + 1*MB;     // 16MB: WTf32 after k1
static constexpr size_t F_V1    = F_V0   + 8*MB;
static constexpr size_t F_U0    = F_V1   + 8*MB;
static constexpr size_t F_U1    = F_U0   + 4*MB;
static constexpr size_t F_QH    = F_U1   + 4*MB;     // W i8 hi plane [1024][4096]
static constexpr size_t F_QL    = F_QH   + 4*MB;     // W i8 lo plane
static constexpr size_t F_SINV  = F_QL   + 4*MB;     // f32[1024]
static constexpr size_t F_H     = F_SINV + 8*MB;     // h u8 [4096][4096]
static constexpr size_t F_BB    = F_H    + 32*MB;    // blockbest [4096][8] float4
static constexpr size_t F_HFLAG = F_BB   + 1*MB;
static constexpr size_t F_RFLAG = F_HFLAG + 512*1024;
static constexpr size_t F_RBEST = F_RFLAG + 16384;
static constexpr size_t F_CNT   = F_RBEST + 16384;
static constexpr size_t F_PREB  = F_CNT  + 256;
static constexpr size_t WS_FULL = F_PREB + 2*MB;

// ---------------- helpers ----------------
__device__ __forceinline__ void gload16(const void* g, void* l) {
    __builtin_amdgcn_global_load_lds(
        (const __attribute__((address_space(1))) void*)g,
        (__attribute__((address_space(3))) void*)l, 16, 0, 0);
}

__device__ __forceinline__ void split1(float x, unsigned short& hi, unsigned short& lo) {
    unsigned u = __float_as_uint(x);
    unsigned r = u + 0x7FFFu + ((u >> 16) & 1u);      // RN-even f32->bf16
    hi = (unsigned short)(r >> 16);
    float rem = x - __uint_as_float(r & 0xFFFF0000u); // exact (Sterbenz)
    unsigned u2 = __float_as_uint(rem);
    unsigned r2 = u2 + 0x7FFFu + ((u2 >> 16) & 1u);
    lo = (unsigned short)(r2 >> 16);
}

__device__ __forceinline__ void merge3(float& b, unsigned& ix, float& s,
                                       float b2, unsigned i2, float s2) {
    if (b2 > b || (b2 == b && i2 < ix)) { s = fmaxf(b, s2); b = b2; ix = i2; }
    else                                { s = fmaxf(s, b2); }
}

// ---------------- prep kernels ----------------
__global__ void kz_zero(unsigned* c) { if (threadIdx.x < 64) c[threadIdx.x] = 0; }

__global__ __launch_bounds__(256) void transpose_split(
    const float* __restrict__ src, int R, int C,
    unsigned short* __restrict__ d0, unsigned short* __restrict__ d1) {
    __shared__ float tile[32][33];
    const int c0 = blockIdx.x * 32, r0 = blockIdx.y * 32;
    const int tx = threadIdx.x & 31, ty = threadIdx.x >> 5;
#pragma unroll
    for (int e = 0; e < 4; ++e)
        tile[ty + e * 8][tx] = src[(size_t)(r0 + ty + e * 8) * C + c0 + tx];
    __syncthreads();
#pragma unroll
    for (int e = 0; e < 4; ++e) {
        int c = c0 + ty + e * 8;
        unsigned short hi, lo;
        split1(tile[tx][ty + e * 8], hi, lo);
        d0[(size_t)c * R + r0 + tx] = hi;
        d1[(size_t)c * R + r0 + tx] = lo;
    }
}

// fused f32 transposes: W (4096x... [1024,4096]->WTf), Bm ([512,4096]->BmTf),
// Am ([512,1024]->ATf). Flat grid decodes which matrix.
__global__ __launch_bounds__(256) void transpose_f32_all(
    const float* __restrict__ W, const float* __restrict__ Bm, const float* __restrict__ Am,
    float* __restrict__ WTf, float* __restrict__ BmTf, float* __restrict__ ATf) {
    __shared__ float tile[32][33];
    int blk = blockIdx.x;
    const float* src; float* dst; int R, C, bx, by;
    if (blk < 4096)      { src = W;  dst = WTf;  R = 1024; C = 4096; blk -= 0;    bx = blk & 127; by = blk >> 7; }
    else if (blk < 6144) { src = Bm; dst = BmTf; R = 512;  C = 4096; blk -= 4096; bx = blk & 127; by = blk >> 7; }
    else                 { src = Am; dst = ATf;  R = 512;  C = 1024; blk -= 6144; bx = blk & 31;  by = blk >> 5; }
    const int c0 = bx * 32, r0 = by * 32;
    const int tx = threadIdx.x & 31, ty = threadIdx.x >> 5;
#pragma unroll
    for (int e = 0; e < 4; ++e)
        tile[ty + e * 8][tx] = src[(size_t)(r0 + ty + e * 8) * C + c0 + tx];
    __syncthreads();
#pragma unroll
    for (int e = 0; e < 4; ++e)
        dst[(size_t)(c0 + ty + e * 8) * R + r0 + tx] = tile[tx][ty + e * 8];
}

__global__ __launch_bounds__(256) void split_planes(
    const float* __restrict__ src, int n4,
    unsigned short* __restrict__ p0, unsigned short* __restrict__ p1) {
    for (int i = blockIdx.x * 256 + threadIdx.x; i < n4; i += gridDim.x * 256) {
        float4 v = ((const float4*)src)[i];
        unsigned short h0,h1,h2,h3,l0,l1,l2,l3;
        split1(v.x,h0,l0); split1(v.y,h1,l1); split1(v.z,h2,l2); split1(v.w,h3,l3);
        ((ushort4*)p0)[i] = make_ushort4(h0,h1,h2,h3);
        ((ushort4*)p1)[i] = make_ushort4(l0,l1,l2,l3);
    }
}

// W rows -> 15-bit fixed point (2 i8 planes + per-row inverse scale)
__global__ __launch_bounds__(256) void quantize_w(
    const float* __restrict__ W, signed char* __restrict__ QH,
    signed char* __restrict__ QL, float* __restrict__ SINV) {
    __shared__ float red[256];
    const int i = blockIdx.x, t = threadIdx.x;
    const float* row = W + (size_t)i * NHID;
    float4 v[4];
    float mx = 0.f;
#pragma unroll
    for (int e = 0; e < 4; ++e) {
        v[e] = *(const float4*)(row + e * 1024 + t * 4);
        mx = fmaxf(mx, fmaxf(fmaxf(fabsf(v[e].x), fabsf(v[e].y)),
                             fmaxf(fabsf(v[e].z), fabsf(v[e].w))));
    }
    red[t] = mx; __syncthreads();
    for (int s = 128; s; s >>= 1) {
        if (t < s) red[t] = fmaxf(red[t], red[t + s]);
        __syncthreads();
    }
    const float rm = fmaxf(red[0], 1e-30f);
    const float sc = 32256.f / rm;
    if (t == 0) SINV[i] = rm / 32256.f;
#pragma unroll
    for (int e = 0; e < 4; ++e) {
        const float* pv = (const float*)&v[e];
        unsigned ph = 0, pl = 0;
#pragma unroll
        for (int j = 0; j < 4; ++j) {
            int wq = (int)lrintf(pv[j] * sc);
            int hi = (wq + 128) >> 8;
            int lo = wq - (hi << 8);
            ph |= ((unsigned)hi & 0xFFu) << (8 * j);
            pl |= ((unsigned)lo & 0xFFu) << (8 * j);
        }
        *(unsigned*)(QH + (size_t)i * NHID + e * 1024 + t * 4) = ph;
        *(unsigned*)(QL + (size_t)i * NHID + e * 1024 + t * 4) = pl;
    }
}

// ===========================================================================
// k1_s4: z = v@W + u@B + c ; h(u8) = noise < sigmoid(z); flag boundary.
// NEW: 128x128 tile, 256 thr / 4 waves (2Mx2N, per-wave 64x64), BK=32,
// SINGLE 32KB buffer, serial stage->sync->compute, FORCED 4 blocks/CU
// (16 waves/CU): cross-block TLP hides stalls (rounds 5/6 k2 evidence).
// A staged on-the-fly from f32 (split in-kernel, round-2-proven; kills vd
// prep). B staged via gload16 from bf16 planes. Chunk-XOR swizzle both.
// grid (32,32)=1024 blocks = 4/CU.
// ===========================================================================
__global__ __launch_bounds__(256, 4) void k1_s4(
    const float* __restrict__ vd, const float* __restrict__ cd,
    const float* __restrict__ noise,
    const unsigned short* __restrict__ WT0, const unsigned short* __restrict__ WT1,
    const unsigned short* __restrict__ BmT0, const unsigned short* __restrict__ BmT1,
    const float* __restrict__ cvec, unsigned char* __restrict__ hout,
    unsigned* __restrict__ hcnt, unsigned* __restrict__ hflag)
{
    __shared__ __align__(16) unsigned short As0[128][32], As1[128][32],
                                            Bs0[128][32], Bs1[128][32];
    const int t = threadIdx.x, lane = t & 63, wid = t >> 6;
    const int g = lane >> 4, cc = lane & 15;
    const int wrow = wid >> 1, wcol = wid & 1;      // 2M x 2N waves, 64x64 each
    const int pc = (g ^ ((cc >> 1) & 3)) * 8;       // swizzled read chunk (proven)
    const int nwg = gridDim.x * gridDim.y;
    const int bid = blockIdx.y * gridDim.x + blockIdx.x;
    const int q = nwg >> 3;
    const int swz = (bid & 7) * q + (bid >> 3);
    const int b0 = (swz / gridDim.x) * 128;
    const int j0 = (swz % gridDim.x) * 128;

    f32x4 acc[4][4] = {};

    for (int ph = 0; ph < 2; ++ph) {
        const int K = ph ? NCOND : NVIS;
        const float* Asrc = ph ? cd : vd;
        const unsigned short* B0 = ph ? BmT0 : WT0;
        const unsigned short* B1 = ph ? BmT1 : WT1;
        for (int k0 = 0; k0 < K; k0 += 32) {
            __syncthreads();   // WAR: prior reads done
            // A: on-the-fly f32 -> bf16 split, ds_write with matching swizzle
#pragma unroll
            for (int e = 0; e < 4; ++e) {
                int idx = t + e * 256, row = idx >> 3, qq = idx & 7;
                const float4 v = *(const float4*)(Asrc + (size_t)(b0 + row) * K + k0 + qq * 4);
                unsigned short h0,h1,h2,h3, s0,s1,s2,s3;
                split1(v.x,h0,s0); split1(v.y,h1,s1); split1(v.z,h2,s2); split1(v.w,h3,s3);
                int c = qq >> 1, sc = c ^ ((row >> 1) & 3);
                int pos = sc * 8 + (qq & 1) * 4;                 // ushort units
                *(ushort4*)&As0[row][pos] = make_ushort4(h0,h1,h2,h3);
                *(ushort4*)&As1[row][pos] = make_ushort4(s0,s1,s2,s3);
            }
            // B: gload16 from planes (linear LDS, pre-swizzled source)
#pragma unroll
            for (int e = 0; e < 2; ++e) {
                int idx = t + e * 256, r = idx >> 2, s = idx & 3;
                int sc = s ^ ((r >> 1) & 3);
                size_t gb = (size_t)(j0 + r) * K + k0 + sc * 8;
                size_t ldd = (size_t)idx * 8;
                gload16(B0 + gb, &Bs0[0][0] + ldd);
                gload16(B1 + gb, &Bs1[0][0] + ldd);
            }
            __syncthreads();   // drains vmcnt+lgkm
            bf16x8 bb0[4], bb1[4];
#pragma unroll
            for (int ni = 0; ni < 4; ++ni) {
                int n = wcol * 64 + ni * 16 + cc;
                bb0[ni] = *(const bf16x8*)&Bs0[n][pc];
                bb1[ni] = *(const bf16x8*)&Bs1[n][pc];
            }
#pragma unroll
            for (int mi = 0; mi < 4; ++mi) {
                int r = wrow * 64 + mi * 16 + cc;
                bf16x8 a0 = *(const bf16x8*)&As0[r][pc];
                bf16x8 a1 = *(const bf16x8*)&As1[r][pc];
#pragma unroll
                for (int ni = 0; ni < 4; ++ni) {
                    acc[mi][ni] = __builtin_amdgcn_mfma_f32_16x16x32_bf16(a0, bb0[ni], acc[mi][ni], 0, 0, 0);
                    acc[mi][ni] = __builtin_amdgcn_mfma_f32_16x16x32_bf16(a0, bb1[ni], acc[mi][ni], 0, 0, 0);
                    acc[mi][ni] = __builtin_amdgcn_mfma_f32_16x16x32_bf16(a1, bb0[ni], acc[mi][ni], 0, 0, 0);
                }
            }
        }
    }

    // epilogue (identical math to proven kernels)
#pragma unroll
    for (int ni = 0; ni < 4; ++ni) {
        int j = j0 + wcol * 64 + ni * 16 + cc;
        float cj = cvec[j];
#pragma unroll
        for (int mi = 0; mi < 4; ++mi) {
#pragma unroll
            for (int i = 0; i < 4; ++i) {
                int b = b0 + wrow * 64 + mi * 16 + g * 4 + i;
                float z = acc[mi][ni][i] + cj;
                float m = 1.0f / (1.0f + __expf(-z));
                float nv = noise[(size_t)b * NHID + j];
                hout[(size_t)b * NHID + j] = (nv < m) ? (unsigned char)1 : (unsigned char)0;
                if (fabsf(nv - m) < 2.5e-4f) {
                    unsigned p = atomicAdd(hcnt, 1u);
                    if (p < HCAP) hflag[p] = ((unsigned)b << 12) | (unsigned)j;
                }
            }
        }
    }
}

// ===========================================================================
// k2_i8: (round-11/12 kernel, unchanged)
// ===========================================================================
__global__ __launch_bounds__(512, 2) void k2_i8(
    const unsigned char* __restrict__ hbf,
    const unsigned short* __restrict__ U0, const unsigned short* __restrict__ U1,
    const signed char* __restrict__ QH, const signed char* __restrict__ QL,
    const float* __restrict__ SINV,
    const unsigned short* __restrict__ AT0, const unsigned short* __restrict__ AT1,
    const float* __restrict__ bvec, float4* __restrict__ blockbest)
{
    __shared__ __align__(16) char smem[32768];
    __shared__ float4 mbuf[4][128];
    const int t = threadIdx.x, lane = t & 63, wid = t >> 6;
    const int g = lane >> 4, cc = lane & 15;
    const int wrow = wid >> 2, wcol = wid & 3;
    const int pcb = (g ^ ((cc >> 1) & 3)) * 16;
    const int nwg = gridDim.x * gridDim.y;
    const int bid = blockIdx.y * gridDim.x + blockIdx.x;
    const int q = nwg >> 3;
    const int swz = (bid & 7) * q + (bid >> 3);
    const int b0 = (swz / gridDim.x) * 128;
    const int i0 = (swz % gridDim.x) * 128;

    char* Ah  = smem;
    char* Qhs = smem + 8192;
    char* Qls = smem + 16384;

    i32x4 ah[4][2] = {}, al[4][2] = {};

    for (int k0 = 0; k0 < NHID; k0 += 64) {
        __syncthreads();
        {
            int r = t >> 2, s = t & 3, sc = s ^ ((r >> 1) & 3);
            size_t off = (size_t)r * 64 + s * 16;
            gload16(hbf + (size_t)(b0 + r) * NHID + k0 + sc * 16, Ah + off);
            gload16(QH + (size_t)(i0 + r) * NHID + k0 + sc * 16, Qhs + off);
            gload16(QL + (size_t)(i0 + r) * NHID + k0 + sc * 16, Qls + off);
        }
        __syncthreads();
        i32x4 bh[2], bl[2];
#pragma unroll
        for (int ni = 0; ni < 2; ++ni) {
            int n = wcol * 32 + ni * 16 + cc;
            bh[ni] = *(const i32x4*)(Qhs + (size_t)n * 64 + pcb);
            bl[ni] = *(const i32x4*)(Qls + (size_t)n * 64 + pcb);
        }
#pragma unroll
        for (int mi = 0; mi < 4; ++mi) {
            i32x4 a = *(const i32x4*)(Ah + (size_t)(wrow * 64 + mi * 16 + cc) * 64 + pcb);
#pragma unroll
            for (int ni = 0; ni < 2; ++ni) {
                ah[mi][ni] = __builtin_amdgcn_mfma_i32_16x16x64_i8(a, bh[ni], ah[mi][ni], 0, 0, 0);
                al[mi][ni] = __builtin_amdgcn_mfma_i32_16x16x64_i8(a, bl[ni], al[mi][ni], 0, 0, 0);
            }
        }
    }
    f32x4 acc[4][2];
#pragma unroll
    for (int ni = 0; ni < 2; ++ni) {
        int col = i0 + wcol * 32 + ni * 16 + cc;
        float sv = SINV[col];
#pragma unroll
        for (int mi = 0; mi < 4; ++mi)
#pragma unroll
            for (int e = 0; e < 4; ++e)
                acc[mi][ni][e] = fmaf(256.f, (float)ah[mi][ni][e], (float)al[mi][ni][e]) * sv;
    }

    char* As0 = smem;
    char* As1 = smem + 8192;
    char* Bs0 = smem + 16384;
    char* Bs1 = smem + 24576;
    for (int k0 = 0; k0 < NCOND; k0 += 32) {
        __syncthreads();
        {
            int r = t >> 2, s = t & 3, sc = s ^ ((r >> 1) & 3);
            size_t off = (size_t)r * 64 + s * 16;
            size_t ga = (size_t)(b0 + r) * NCOND + k0 + sc * 8;
            gload16(U0 + ga, As0 + off);
            gload16(U1 + ga, As1 + off);
            size_t go = (size_t)(i0 + r) * NCOND + k0 + sc * 8;
            gload16(AT0 + go, Bs0 + off);
            gload16(AT1 + go, Bs1 + off);
        }
        __syncthreads();
        bf16x8 bb0[2], bb1[2];
#pragma unroll
        for (int ni = 0; ni < 2; ++ni) {
            int n = wcol * 32 + ni * 16 + cc;
            bb0[ni] = *(const bf16x8*)(Bs0 + (size_t)n * 64 + pcb);
            bb1[ni] = *(const bf16x8*)(Bs1 + (size_t)n * 64 + pcb);
        }
#pragma unroll
        for (int mi = 0; mi < 4; ++mi) {
            int r = wrow * 64 + mi * 16 + cc;
            bf16x8 a0 = *(const bf16x8*)(As0 + (size_t)r * 64 + pcb);
            bf16x8 a1 = *(const bf16x8*)(As1 + (size_t)r * 64 + pcb);
#pragma unroll
            for (int ni = 0; ni < 2; ++ni) {
                acc[mi][ni] = __builtin_amdgcn_mfma_f32_16x16x32_bf16(a0, bb0[ni], acc[mi][ni], 0, 0, 0);
                acc[mi][ni] = __builtin_amdgcn_mfma_f32_16x16x32_bf16(a0, bb1[ni], acc[mi][ni], 0, 0, 0);
                acc[mi][ni] = __builtin_amdgcn_mfma_f32_16x16x32_bf16(a1, bb0[ni], acc[mi][ni], 0, 0, 0);
            }
        }
    }

#pragma unroll
    for (int ni = 0; ni < 2; ++ni) {
        int colb = i0 + wcol * 32 + ni * 16 + cc;
        float bb = bvec[colb];
#pragma unroll
        for (int mi = 0; mi < 4; ++mi)
#pragma unroll
            for (int i = 0; i < 4; ++i) acc[mi][ni][i] += bb;
    }
#pragma unroll
    for (int mi = 0; mi < 4; ++mi) {
#pragma unroll
        for (int i = 0; i < 4; ++i) {
            float best = acc[mi][0][i];
            unsigned bidx = (unsigned)(i0 + wcol * 32 + cc);
            float sec = -3.4e38f;
            merge3(best, bidx, sec, acc[mi][1][i],
                   (unsigned)(i0 + wcol * 32 + 16 + cc), -3.4e38f);
#pragma unroll
            for (int m = 1; m < 16; m <<= 1) {
                float ob = __shfl_xor(best, m);
                unsigned oi = __shfl_xor(bidx, m);
                float os = __shfl_xor(sec, m);
                merge3(best, bidx, sec, ob, oi, os);
            }
            if (cc == 0)
                mbuf[wcol][wrow * 64 + mi * 16 + g * 4 + i] =
                    make_float4(best, sec, __uint_as_float(bidx), 0.f);
        }
    }
    __syncthreads();
    if (t < 128) {
        float4 f0 = mbuf[0][t];
        float best = f0.x, sec = f0.y;
        unsigned bidx = __float_as_uint(f0.z);
#pragma unroll
        for (int wq = 1; wq < 4; ++wq) {
            float4 fq = mbuf[wq][t];
            merge3(best, bidx, sec, fq.x, __float_as_uint(fq.z), fq.y);
        }
        blockbest[(size_t)(b0 + t) * 8 + (unsigned)(i0 >> 7)] =
            make_float4(best, sec, __uint_as_float(bidx), 0.f);
    }
}

// ---------------- k5: exact f64 recheck, coalesced (h u8) -------------------
__global__ __launch_bounds__(256) void k5_recheck_h(
    const float* __restrict__ vd, const float* __restrict__ cd, const float* __restrict__ noise,
    const float* __restrict__ WTf, const float* __restrict__ BmTf, const float* __restrict__ cvec,
    const unsigned* __restrict__ hcnt, const unsigned* __restrict__ hflag,
    unsigned char* __restrict__ h) {
    const int gw = (blockIdx.x * 256 + threadIdx.x) >> 6, lane = threadIdx.x & 63;
    const int nw = gridDim.x * 4;
    unsigned n = *hcnt; if (n > HCAP) n = HCAP;
    for (unsigned e = gw; e < n; e += nw) {
        unsigned p = hflag[e];
        int b = p >> 12, j = p & 4095;
        double s = 0.0;
        for (int k = lane; k < NVIS; k += 64)
            s += (double)vd[(size_t)b * NVIS + k] * (double)WTf[(size_t)j * NVIS + k];
        for (int k = lane; k < NCOND; k += 64)
            s += (double)cd[(size_t)b * NCOND + k] * (double)BmTf[(size_t)j * NCOND + k];
        for (int m = 32; m; m >>= 1) s += __shfl_xor(s, m);
        if (lane == 0) {
            double z = s + (double)cvec[j];
            double mm = 1.0 / (1.0 + exp(-z));
            h[(size_t)b * NHID + j] =
                ((double)noise[(size_t)b * NHID + j] < mm) ? (unsigned char)1 : (unsigned char)0;
        }
    }
}

// ---------------- k3: merge 8 block-top2 per row; flag near-ties -----------
__global__ __launch_bounds__(256) void k3_merge8(
    const float4* __restrict__ blockbest, unsigned* __restrict__ rowbest,
    unsigned* __restrict__ rcnt, unsigned* __restrict__ rowflag) {
    const int t = threadIdx.x;
    const int row = blockIdx.x * 32 + (t >> 3), e = t & 7;
    float4 f = blockbest[(size_t)row * 8 + e];
    float best = f.x, sec = f.y;
    unsigned idx = __float_as_uint(f.z);
#pragma unroll
    for (int m = 1; m < 8; m <<= 1) {
        float ob = __shfl_xor(best, m);
        unsigned oi = __shfl_xor(idx, m);
        float os = __shfl_xor(sec, m);
        merge3(best, idx, sec, ob, oi, os);
    }
    if (e == 0) {
        rowbest[row] = idx;
        if (best - sec < 4e-3f) {
            unsigned p = atomicAdd(rcnt, 1u);
            if (p < 4096) rowflag[p] = (unsigned)row;
        }
    }
}

// ---------------- onehot write (all rows, fast-path argmax) ----------------
__global__ __launch_bounds__(256) void k_onehot(const unsigned* __restrict__ rowbest,
                                                float* __restrict__ out) {
    const int row = blockIdx.x;
    const unsigned idx = rowbest[row];
    const int base = threadIdx.x * 4;
    float4 o;
    o.x = (base + 0 == (int)idx) ? 1.f : 0.f;
    o.y = (base + 1 == (int)idx) ? 1.f : 0.f;
    o.z = (base + 2 == (int)idx) ? 1.f : 0.f;
    o.w = (base + 3 == (int)idx) ? 1.f : 0.f;
    *(float4*)(out + (size_t)row * NVIS + base) = o;
}

// ---------------- k6a: exact f64 pre for flagged rows (h u8) ---------------
__global__ __launch_bounds__(256) void k6_rows_pre(
    const unsigned char* __restrict__ h, const float* __restrict__ cd,
    const float* __restrict__ W, const float* __restrict__ ATf, const float* __restrict__ bvec,
    const unsigned* __restrict__ rcnt, const unsigned* __restrict__ rowflag,
    double* __restrict__ prebuf) {
    const int gw = (blockIdx.x * 256 + threadIdx.x) >> 6, lane = threadIdx.x & 63;
    const int nw = gridDim.x * 4;
    unsigned n = *rcnt; if (n > RCAP) n = RCAP;
    for (unsigned e = gw; e < n * 1024u; e += nw) {
        int ri = e >> 10, i = e & 1023;
        int b = (int)rowflag[ri];
        double s = 0.0;
        for (int k = lane; k < NHID; k += 64) {
            double hv = h[(size_t)b * NHID + k] ? 1.0 : 0.0;
            s += hv * (double)W[(size_t)i * NHID + k];
        }
        for (int k = lane; k < NCOND; k += 64)
            s += (double)cd[(size_t)b * NCOND + k] * (double)ATf[(size_t)i * NCOND + k];
        for (int m = 32; m; m >>= 1) s += __shfl_xor(s, m);
        if (lane == 0) prebuf[(size_t)ri * 1024 + i] = s + (double)bvec[i];
    }
}

// ---------------- k6b: exact argmax + rewrite flagged rows -----------------
__global__ __launch_bounds__(256) void k6_rows_argmax(
    const unsigned* __restrict__ rcnt, const unsigned* __restrict__ rowflag,
    const double* __restrict__ prebuf, float* __restrict__ out) {
    __shared__ double sv[256];
    __shared__ int si[256];
    unsigned n = *rcnt; if (n > RCAP) n = RCAP;
    const int t = threadIdx.x;
    for (unsigned ri = blockIdx.x; ri < n; ri += gridDim.x) {
        const int row = (int)rowflag[ri];
        const double* pr = prebuf + (size_t)ri * 1024;
        double best = pr[t * 4];
        int bi = t * 4;
#pragma unroll
        for (int e = 1; e < 4; ++e) {
            double v = pr[t * 4 + e];
            if (v > best) { best = v; bi = t * 4 + e; }
        }
        sv[t] = best; si[t] = bi;
        __syncthreads();
        for (int s = 128; s; s >>= 1) {
            if (t < s) {
                double v2 = sv[t + s]; int i2 = si[t + s];
                if (v2 > sv[t] || (v2 == sv[t] && i2 < si[t])) { sv[t] = v2; si[t] = i2; }
            }
            __syncthreads();
        }
        const int amax = si[0];
        const int base = t * 4;
        float4 o;
        o.x = (base + 0 == amax) ? 1.f : 0.f;
        o.y = (base + 1 == amax) ? 1.f : 0.f;
        o.z = (base + 2 == amax) ? 1.f : 0.f;
        o.w = (base + 3 == amax) ? 1.f : 0.f;
        *(float4*)(out + (size_t)row * NVIS + base) = o;
        __syncthreads();
    }
}

// ---------------- launch ----------------
extern "C" void kernel_launch(void* const* d_in, const int* in_sizes, int n_in,
                              void* d_out, int out_size, void* d_ws, size_t ws_size,
                              hipStream_t stream) {
    const float* vd = (const float*)d_in[0];  // [4096,1024]
    const float* cd = (const float*)d_in[1];  // [4096,512]
    const float* nz = (const float*)d_in[2];  // [4096,4096]
    const float* W  = (const float*)d_in[3];  // [1024,4096]
    const float* bv = (const float*)d_in[4];  // [1024]
    const float* cv = (const float*)d_in[5];  // [4096]
    const float* Am = (const float*)d_in[6];  // [512,1024]
    const float* Bm = (const float*)d_in[7];  // [512,4096]
    float* out = (float*)d_out;
    char* w = (char*)d_ws;

    unsigned short* WT0  = (unsigned short*)(w + F_WT0);
    unsigned short* WT1  = (unsigned short*)(w + F_WT1);
    unsigned short* BmT0 = (unsigned short*)(w + F_BMT0);
    unsigned short* BmT1 = (unsigned short*)(w + F_BMT1);
    unsigned short* AT0  = (unsigned short*)(w + F_AT0);
    unsigned short* AT1  = (unsigned short*)(w + F_AT1);
    unsigned short* U0   = (unsigned short*)(w + F_U0);
    unsigned short* U1   = (unsigned short*)(w + F_U1);
    signed char*    QH   = (signed char*)(w + F_QH);
    signed char*    QL   = (signed char*)(w + F_QL);
    float*          SINV = (float*)(w + F_SINV);
    unsigned char*  hbf  = (unsigned char*)(w + F_H);
    float4*   blockbest  = (float4*)(w + F_BB);
    unsigned* hflag      = (unsigned*)(w + F_HFLAG);
    unsigned* rowflag    = (unsigned*)(w + F_RFLAG);
    unsigned* rowbest    = (unsigned*)(w + F_RBEST);
    unsigned* counters   = (unsigned*)(w + F_CNT);
    double*   prebuf     = (double*)(w + F_PREB);
    unsigned* hcnt = &counters[0];
    unsigned* rcnt = &counters[1];
    float* WTf32  = (float*)(w + F_V0);    // [4096][1024] 16MB (V region, unused now)
    float* BmTf32 = (float*)(w + F_WT0);   // [4096][512]   8MB (dead after k1)
    float* ATf32  = (float*)(w + F_WT1);   // [1024][512]   2MB (dead after k1)

    dim3 blk(256);
    kz_zero<<<1, 64, 0, stream>>>(counters);
    transpose_split<<<dim3(NHID / 32, NVIS / 32), blk, 0, stream>>>(W, NVIS, NHID, WT0, WT1);
    transpose_split<<<dim3(NHID / 32, NCOND / 32), blk, 0, stream>>>(Bm, NCOND, NHID, BmT0, BmT1);
    transpose_split<<<dim3(NVIS / 32, NCOND / 32), blk, 0, stream>>>(Am, NCOND, NVIS, AT0, AT1);
    split_planes<<<2048, blk, 0, stream>>>(cd, BATCH * NCOND / 4, U0, U1);
    quantize_w<<<NVIS, blk, 0, stream>>>(W, QH, QL, SINV);
    k1_s4<<<dim3(NHID / 128, BATCH / 128), blk, 0, stream>>>(
        vd, cd, nz, WT0, WT1, BmT0, BmT1, cv, hbf, hcnt, hflag);
    transpose_f32_all<<<6656, blk, 0, stream>>>(W, Bm, Am, WTf32, BmTf32, ATf32);
    k5_recheck_h<<<256, blk, 0, stream>>>(vd, cd, nz, WTf32, BmTf32, cv, hcnt, hflag, hbf);
    k2_i8<<<dim3(NVIS / 128, BATCH / 128), 512, 0, stream>>>(
        hbf, U0, U1, QH, QL, SINV, AT0, AT1, bv, blockbest);
    k3_merge8<<<BATCH / 32, blk, 0, stream>>>(blockbest, rowbest, rcnt, rowflag);
    k_onehot<<<BATCH, blk, 0, stream>>>(rowbest, out);
    k6_rows_pre<<<512, blk, 0, stream>>>(hbf, cd, W, ATf32, bv, rcnt, rowflag, prebuf);
    k6_rows_argmax<<<64, blk, 0, stream>>>(rcnt, rowflag, prebuf, out);
}

// Round 14
// 528.813 us; speedup vs baseline: 1.0860x; 1.0860x over previous
//
#include <hip/hip_runtime.h>
#include <math.h>

static constexpr int BATCH = 4096;
static constexpr int NVIS  = 1024;
static constexpr int NHID  = 4096;
static constexpr int NCOND = 512;

typedef __attribute__((ext_vector_type(8))) short bf16x8;
typedef __attribute__((ext_vector_type(4))) float f32x4;
typedef __attribute__((ext_vector_type(4))) int   i32x4;

static constexpr unsigned HCAP = 131072;
static constexpr unsigned RCAP = 256;
static constexpr size_t MB = 1u << 20;

// ---------------- ws layout (proven) ----------------
static constexpr size_t F_WT0   = 0;                 // W^T bf16 planes (dead after k1)
static constexpr size_t F_WT1   = F_WT0  + 8*MB;
static constexpr size_t F_BMT0  = F_WT1  + 8*MB;
static constexpr size_t F_BMT1  = F_BMT0 + 4*MB;
static constexpr size_t F_AT0   = F_BMT1 + 4*MB;
static constexpr size_t F_AT1   = F_AT0  + 1*MB;
static constexpr size_t F_V0    = F_AT1  + 1*MB;     // vd planes (dead after k1 -> WTf32)
static constexpr size_t F_V1    = F_V0   + 8*MB;
static constexpr size_t F_U0    = F_V1   + 8*MB;
static constexpr size_t F_U1    = F_U0   + 4*MB;
static constexpr size_t F_QH    = F_U1   + 4*MB;     // W i8 hi plane [1024][4096]
static constexpr size_t F_QL    = F_QH   + 4*MB;     // W i8 lo plane
static constexpr size_t F_SINV  = F_QL   + 4*MB;     // f32[1024]
static constexpr size_t F_H     = F_SINV + 8*MB;     // h u8 [4096][4096]
static constexpr size_t F_BB    = F_H    + 32*MB;    // blockbest [4096][8] float4
static constexpr size_t F_HFLAG = F_BB   + 1*MB;
static constexpr size_t F_RFLAG = F_HFLAG + 512*1024;
static constexpr size_t F_RBEST = F_RFLAG + 16384;
static constexpr size_t F_CNT   = F_RBEST + 16384;
static constexpr size_t F_PREB  = F_CNT  + 256;
static constexpr size_t WS_FULL = F_PREB + 2*MB;

// ---------------- helpers ----------------
__device__ __forceinline__ void gload16(const void* g, void* l) {
    __builtin_amdgcn_global_load_lds(
        (const __attribute__((address_space(1))) void*)g,
        (__attribute__((address_space(3))) void*)l, 16, 0, 0);
}

__device__ __forceinline__ void split1(float x, unsigned short& hi, unsigned short& lo) {
    unsigned u = __float_as_uint(x);
    unsigned r = u + 0x7FFFu + ((u >> 16) & 1u);      // RN-even f32->bf16
    hi = (unsigned short)(r >> 16);
    float rem = x - __uint_as_float(r & 0xFFFF0000u); // exact (Sterbenz)
    unsigned u2 = __float_as_uint(rem);
    unsigned r2 = u2 + 0x7FFFu + ((u2 >> 16) & 1u);
    lo = (unsigned short)(r2 >> 16);
}

__device__ __forceinline__ void merge3(float& b, unsigned& ix, float& s,
                                       float b2, unsigned i2, float s2) {
    if (b2 > b || (b2 == b && i2 < ix)) { s = fmaxf(b, s2); b = b2; ix = i2; }
    else                                { s = fmaxf(s, b2); }
}

// ---------------- prep kernels ----------------
__global__ void kz_zero(unsigned* c) { if (threadIdx.x < 64) c[threadIdx.x] = 0; }

__global__ __launch_bounds__(256) void transpose_split(
    const float* __restrict__ src, int R, int C,
    unsigned short* __restrict__ d0, unsigned short* __restrict__ d1) {
    __shared__ float tile[32][33];
    const int c0 = blockIdx.x * 32, r0 = blockIdx.y * 32;
    const int tx = threadIdx.x & 31, ty = threadIdx.x >> 5;
#pragma unroll
    for (int e = 0; e < 4; ++e)
        tile[ty + e * 8][tx] = src[(size_t)(r0 + ty + e * 8) * C + c0 + tx];
    __syncthreads();
#pragma unroll
    for (int e = 0; e < 4; ++e) {
        int c = c0 + ty + e * 8;
        unsigned short hi, lo;
        split1(tile[tx][ty + e * 8], hi, lo);
        d0[(size_t)c * R + r0 + tx] = hi;
        d1[(size_t)c * R + r0 + tx] = lo;
    }
}

// fused f32 transposes: W [1024,4096]->WTf, Bm [512,4096]->BmTf, Am [512,1024]->ATf
__global__ __launch_bounds__(256) void transpose_f32_all(
    const float* __restrict__ W, const float* __restrict__ Bm, const float* __restrict__ Am,
    float* __restrict__ WTf, float* __restrict__ BmTf, float* __restrict__ ATf) {
    __shared__ float tile[32][33];
    int blk = blockIdx.x;
    const float* src; float* dst; int R, C, bx, by;
    if (blk < 4096)      { src = W;  dst = WTf;  R = 1024; C = 4096; blk -= 0;    bx = blk & 127; by = blk >> 7; }
    else if (blk < 6144) { src = Bm; dst = BmTf; R = 512;  C = 4096; blk -= 4096; bx = blk & 127; by = blk >> 7; }
    else                 { src = Am; dst = ATf;  R = 512;  C = 1024; blk -= 6144; bx = blk & 31;  by = blk >> 5; }
    const int c0 = bx * 32, r0 = by * 32;
    const int tx = threadIdx.x & 31, ty = threadIdx.x >> 5;
#pragma unroll
    for (int e = 0; e < 4; ++e)
        tile[ty + e * 8][tx] = src[(size_t)(r0 + ty + e * 8) * C + c0 + tx];
    __syncthreads();
#pragma unroll
    for (int e = 0; e < 4; ++e)
        dst[(size_t)(c0 + ty + e * 8) * R + r0 + tx] = tile[tx][ty + e * 8];
}

__global__ __launch_bounds__(256) void split_planes(
    const float* __restrict__ src, int n4,
    unsigned short* __restrict__ p0, unsigned short* __restrict__ p1) {
    for (int i = blockIdx.x * 256 + threadIdx.x; i < n4; i += gridDim.x * 256) {
        float4 v = ((const float4*)src)[i];
        unsigned short h0,h1,h2,h3,l0,l1,l2,l3;
        split1(v.x,h0,l0); split1(v.y,h1,l1); split1(v.z,h2,l2); split1(v.w,h3,l3);
        ((ushort4*)p0)[i] = make_ushort4(h0,h1,h2,h3);
        ((ushort4*)p1)[i] = make_ushort4(l0,l1,l2,l3);
    }
}

// W rows -> 15-bit fixed point (2 i8 planes + per-row inverse scale)
__global__ __launch_bounds__(256) void quantize_w(
    const float* __restrict__ W, signed char* __restrict__ QH,
    signed char* __restrict__ QL, float* __restrict__ SINV) {
    __shared__ float red[256];
    const int i = blockIdx.x, t = threadIdx.x;
    const float* row = W + (size_t)i * NHID;
    float4 v[4];
    float mx = 0.f;
#pragma unroll
    for (int e = 0; e < 4; ++e) {
        v[e] = *(const float4*)(row + e * 1024 + t * 4);
        mx = fmaxf(mx, fmaxf(fmaxf(fabsf(v[e].x), fabsf(v[e].y)),
                             fmaxf(fabsf(v[e].z), fabsf(v[e].w))));
    }
    red[t] = mx; __syncthreads();
    for (int s = 128; s; s >>= 1) {
        if (t < s) red[t] = fmaxf(red[t], red[t + s]);
        __syncthreads();
    }
    const float rm = fmaxf(red[0], 1e-30f);
    const float sc = 32256.f / rm;
    if (t == 0) SINV[i] = rm / 32256.f;
#pragma unroll
    for (int e = 0; e < 4; ++e) {
        const float* pv = (const float*)&v[e];
        unsigned ph = 0, pl = 0;
#pragma unroll
        for (int j = 0; j < 4; ++j) {
            int wq = (int)lrintf(pv[j] * sc);
            int hi = (wq + 128) >> 8;
            int lo = wq - (hi << 8);
            ph |= ((unsigned)hi & 0xFFu) << (8 * j);
            pl |= ((unsigned)lo & 0xFFu) << (8 * j);
        }
        *(unsigned*)(QH + (size_t)i * NHID + e * 1024 + t * 4) = ph;
        *(unsigned*)(QL + (size_t)i * NHID + e * 1024 + t * 4) = pl;
    }
}

// ===========================================================================
// k1_t2: z = v@W + u@B + c ; h(u8) = noise < sigmoid(z); flag boundary.
// 256x256 tile (805MB staged, minimal), BK=32, SINGLE 64KB buffer, serial
// stage->sync->compute, __launch_bounds__(512,2) = 2 blocks/CU (16 waves/CU):
// round-13 evidence says staged-delivery BW scales with blocks/CU.
// Proven chunk-XOR swizzle + round-7 compute body. grid (16,16)=256.
// ===========================================================================
__global__ __launch_bounds__(512, 2) void k1_t2(
    const float* __restrict__ noise,
    const unsigned short* __restrict__ V0, const unsigned short* __restrict__ V1,
    const unsigned short* __restrict__ U0, const unsigned short* __restrict__ U1,
    const unsigned short* __restrict__ WT0, const unsigned short* __restrict__ WT1,
    const unsigned short* __restrict__ BmT0, const unsigned short* __restrict__ BmT1,
    const float* __restrict__ cvec, unsigned char* __restrict__ hout,
    unsigned* __restrict__ hcnt, unsigned* __restrict__ hflag)
{
    __shared__ __align__(16) unsigned short As0[256][32], As1[256][32],
                                            Bs0[256][32], Bs1[256][32];
    const int t = threadIdx.x, lane = t & 63, wid = t >> 6;
    const int g = lane >> 4, cc = lane & 15;
    const int wrow = wid >> 2, wcol = wid & 3;      // 2M x 4N waves
    const int pc = (g ^ ((cc >> 1) & 3)) * 8;       // swizzled read chunk (proven)
    const int nwg = gridDim.x * gridDim.y;
    const int bid = blockIdx.y * gridDim.x + blockIdx.x;
    const int q = nwg >> 3;
    const int swz = (bid & 7) * q + (bid >> 3);
    const int b0 = (swz / gridDim.x) * 256;
    const int j0 = (swz % gridDim.x) * 256;

    f32x4 acc[8][4] = {};

    for (int tt = 0; tt < 48; ++tt) {
        const unsigned short *A0_, *A1_, *B0_, *B1_; int K_, k0_;
        if (tt < 32) { A0_ = V0; A1_ = V1; B0_ = WT0; B1_ = WT1; K_ = 1024; k0_ = tt * 32; }
        else         { A0_ = U0; A1_ = U1; B0_ = BmT0; B1_ = BmT1; K_ = 512; k0_ = (tt - 32) * 32; }
        __syncthreads();   // WAR: prior step's reads done
#pragma unroll
        for (int e = 0; e < 2; ++e) {
            int idx = t + e * 512, r = idx >> 2, s = idx & 3;
            int sc = s ^ ((r >> 1) & 3);            // pre-swizzled source chunk
            size_t ga = (size_t)(b0 + r) * K_ + k0_ + sc * 8;
            size_t gb = (size_t)(j0 + r) * K_ + k0_ + sc * 8;
            size_t ldd = (size_t)idx * 8;           // linear LDS dest (ushorts)
            gload16(A0_ + ga, &As0[0][0] + ldd);
            gload16(A1_ + ga, &As1[0][0] + ldd);
            gload16(B0_ + gb, &Bs0[0][0] + ldd);
            gload16(B1_ + gb, &Bs1[0][0] + ldd);
        }
        __syncthreads();   // drains vmcnt: tile visible
        bf16x8 bb0[4], bb1[4];
#pragma unroll
        for (int ni = 0; ni < 4; ++ni) {
            int n = wcol * 64 + ni * 16 + cc;
            bb0[ni] = *(const bf16x8*)&Bs0[n][pc];
            bb1[ni] = *(const bf16x8*)&Bs1[n][pc];
        }
#pragma unroll
        for (int mi = 0; mi < 8; ++mi) {
            int r = wrow * 128 + mi * 16 + cc;
            bf16x8 a0 = *(const bf16x8*)&As0[r][pc];
            bf16x8 a1 = *(const bf16x8*)&As1[r][pc];
#pragma unroll
            for (int ni = 0; ni < 4; ++ni) {
                acc[mi][ni] = __builtin_amdgcn_mfma_f32_16x16x32_bf16(a0, bb0[ni], acc[mi][ni], 0, 0, 0);
                acc[mi][ni] = __builtin_amdgcn_mfma_f32_16x16x32_bf16(a0, bb1[ni], acc[mi][ni], 0, 0, 0);
                acc[mi][ni] = __builtin_amdgcn_mfma_f32_16x16x32_bf16(a1, bb0[ni], acc[mi][ni], 0, 0, 0);
            }
        }
    }

    // epilogue (identical math to proven kernels)
#pragma unroll
    for (int ni = 0; ni < 4; ++ni) {
        int j = j0 + wcol * 64 + ni * 16 + cc;
        float cj = cvec[j];
#pragma unroll
        for (int mi = 0; mi < 8; ++mi) {
#pragma unroll
            for (int i = 0; i < 4; ++i) {
                int b = b0 + wrow * 128 + mi * 16 + g * 4 + i;
                float z = acc[mi][ni][i] + cj;
                float m = 1.0f / (1.0f + __expf(-z));
                float nv = noise[(size_t)b * NHID + j];
                hout[(size_t)b * NHID + j] = (nv < m) ? (unsigned char)1 : (unsigned char)0;
                if (fabsf(nv - m) < 2.5e-4f) {
                    unsigned p = atomicAdd(hcnt, 1u);
                    if (p < HCAP) hflag[p] = ((unsigned)b << 12) | (unsigned)j;
                }
            }
        }
    }
}

// ===========================================================================
// k2_i8: (round-11/12 kernel, unchanged)
// ===========================================================================
__global__ __launch_bounds__(512, 2) void k2_i8(
    const unsigned char* __restrict__ hbf,
    const unsigned short* __restrict__ U0, const unsigned short* __restrict__ U1,
    const signed char* __restrict__ QH, const signed char* __restrict__ QL,
    const float* __restrict__ SINV,
    const unsigned short* __restrict__ AT0, const unsigned short* __restrict__ AT1,
    const float* __restrict__ bvec, float4* __restrict__ blockbest)
{
    __shared__ __align__(16) char smem[32768];
    __shared__ float4 mbuf[4][128];
    const int t = threadIdx.x, lane = t & 63, wid = t >> 6;
    const int g = lane >> 4, cc = lane & 15;
    const int wrow = wid >> 2, wcol = wid & 3;
    const int pcb = (g ^ ((cc >> 1) & 3)) * 16;
    const int nwg = gridDim.x * gridDim.y;
    const int bid = blockIdx.y * gridDim.x + blockIdx.x;
    const int q = nwg >> 3;
    const int swz = (bid & 7) * q + (bid >> 3);
    const int b0 = (swz / gridDim.x) * 128;
    const int i0 = (swz % gridDim.x) * 128;

    char* Ah  = smem;
    char* Qhs = smem + 8192;
    char* Qls = smem + 16384;

    i32x4 ah[4][2] = {}, al[4][2] = {};

    for (int k0 = 0; k0 < NHID; k0 += 64) {
        __syncthreads();
        {
            int r = t >> 2, s = t & 3, sc = s ^ ((r >> 1) & 3);
            size_t off = (size_t)r * 64 + s * 16;
            gload16(hbf + (size_t)(b0 + r) * NHID + k0 + sc * 16, Ah + off);
            gload16(QH + (size_t)(i0 + r) * NHID + k0 + sc * 16, Qhs + off);
            gload16(QL + (size_t)(i0 + r) * NHID + k0 + sc * 16, Qls + off);
        }
        __syncthreads();
        i32x4 bh[2], bl[2];
#pragma unroll
        for (int ni = 0; ni < 2; ++ni) {
            int n = wcol * 32 + ni * 16 + cc;
            bh[ni] = *(const i32x4*)(Qhs + (size_t)n * 64 + pcb);
            bl[ni] = *(const i32x4*)(Qls + (size_t)n * 64 + pcb);
        }
#pragma unroll
        for (int mi = 0; mi < 4; ++mi) {
            i32x4 a = *(const i32x4*)(Ah + (size_t)(wrow * 64 + mi * 16 + cc) * 64 + pcb);
#pragma unroll
            for (int ni = 0; ni < 2; ++ni) {
                ah[mi][ni] = __builtin_amdgcn_mfma_i32_16x16x64_i8(a, bh[ni], ah[mi][ni], 0, 0, 0);
                al[mi][ni] = __builtin_amdgcn_mfma_i32_16x16x64_i8(a, bl[ni], al[mi][ni], 0, 0, 0);
            }
        }
    }
    f32x4 acc[4][2];
#pragma unroll
    for (int ni = 0; ni < 2; ++ni) {
        int col = i0 + wcol * 32 + ni * 16 + cc;
        float sv = SINV[col];
#pragma unroll
        for (int mi = 0; mi < 4; ++mi)
#pragma unroll
            for (int e = 0; e < 4; ++e)
                acc[mi][ni][e] = fmaf(256.f, (float)ah[mi][ni][e], (float)al[mi][ni][e]) * sv;
    }

    char* As0 = smem;
    char* As1 = smem + 8192;
    char* Bs0 = smem + 16384;
    char* Bs1 = smem + 24576;
    for (int k0 = 0; k0 < NCOND; k0 += 32) {
        __syncthreads();
        {
            int r = t >> 2, s = t & 3, sc = s ^ ((r >> 1) & 3);
            size_t off = (size_t)r * 64 + s * 16;
            size_t ga = (size_t)(b0 + r) * NCOND + k0 + sc * 8;
            gload16(U0 + ga, As0 + off);
            gload16(U1 + ga, As1 + off);
            size_t go = (size_t)(i0 + r) * NCOND + k0 + sc * 8;
            gload16(AT0 + go, Bs0 + off);
            gload16(AT1 + go, Bs1 + off);
        }
        __syncthreads();
        bf16x8 bb0[2], bb1[2];
#pragma unroll
        for (int ni = 0; ni < 2; ++ni) {
            int n = wcol * 32 + ni * 16 + cc;
            bb0[ni] = *(const bf16x8*)(Bs0 + (size_t)n * 64 + pcb);
            bb1[ni] = *(const bf16x8*)(Bs1 + (size_t)n * 64 + pcb);
        }
#pragma unroll
        for (int mi = 0; mi < 4; ++mi) {
            int r = wrow * 64 + mi * 16 + cc;
            bf16x8 a0 = *(const bf16x8*)(As0 + (size_t)r * 64 + pcb);
            bf16x8 a1 = *(const bf16x8*)(As1 + (size_t)r * 64 + pcb);
#pragma unroll
            for (int ni = 0; ni < 2; ++ni) {
                acc[mi][ni] = __builtin_amdgcn_mfma_f32_16x16x32_bf16(a0, bb0[ni], acc[mi][ni], 0, 0, 0);
                acc[mi][ni] = __builtin_amdgcn_mfma_f32_16x16x32_bf16(a0, bb1[ni], acc[mi][ni], 0, 0, 0);
                acc[mi][ni] = __builtin_amdgcn_mfma_f32_16x16x32_bf16(a1, bb0[ni], acc[mi][ni], 0, 0, 0);
            }
        }
    }

#pragma unroll
    for (int ni = 0; ni < 2; ++ni) {
        int colb = i0 + wcol * 32 + ni * 16 + cc;
        float bb = bvec[colb];
#pragma unroll
        for (int mi = 0; mi < 4; ++mi)
#pragma unroll
            for (int i = 0; i < 4; ++i) acc[mi][ni][i] += bb;
    }
#pragma unroll
    for (int mi = 0; mi < 4; ++mi) {
#pragma unroll
        for (int i = 0; i < 4; ++i) {
            float best = acc[mi][0][i];
            unsigned bidx = (unsigned)(i0 + wcol * 32 + cc);
            float sec = -3.4e38f;
            merge3(best, bidx, sec, acc[mi][1][i],
                   (unsigned)(i0 + wcol * 32 + 16 + cc), -3.4e38f);
#pragma unroll
            for (int m = 1; m < 16; m <<= 1) {
                float ob = __shfl_xor(best, m);
                unsigned oi = __shfl_xor(bidx, m);
                float os = __shfl_xor(sec, m);
                merge3(best, bidx, sec, ob, oi, os);
            }
            if (cc == 0)
                mbuf[wcol][wrow * 64 + mi * 16 + g * 4 + i] =
                    make_float4(best, sec, __uint_as_float(bidx), 0.f);
        }
    }
    __syncthreads();
    if (t < 128) {
        float4 f0 = mbuf[0][t];
        float best = f0.x, sec = f0.y;
        unsigned bidx = __float_as_uint(f0.z);
#pragma unroll
        for (int wq = 1; wq < 4; ++wq) {
            float4 fq = mbuf[wq][t];
            merge3(best, bidx, sec, fq.x, __float_as_uint(fq.z), fq.y);
        }
        blockbest[(size_t)(b0 + t) * 8 + (unsigned)(i0 >> 7)] =
            make_float4(best, sec, __uint_as_float(bidx), 0.f);
    }
}

// ---------------- k5: exact f64 recheck, coalesced (h u8) -------------------
__global__ __launch_bounds__(256) void k5_recheck_h(
    const float* __restrict__ vd, const float* __restrict__ cd, const float* __restrict__ noise,
    const float* __restrict__ WTf, const float* __restrict__ BmTf, const float* __restrict__ cvec,
    const unsigned* __restrict__ hcnt, const unsigned* __restrict__ hflag,
    unsigned char* __restrict__ h) {
    const int gw = (blockIdx.x * 256 + threadIdx.x) >> 6, lane = threadIdx.x & 63;
    const int nw = gridDim.x * 4;
    unsigned n = *hcnt; if (n > HCAP) n = HCAP;
    for (unsigned e = gw; e < n; e += nw) {
        unsigned p = hflag[e];
        int b = p >> 12, j = p & 4095;
        double s = 0.0;
        for (int k = lane; k < NVIS; k += 64)
            s += (double)vd[(size_t)b * NVIS + k] * (double)WTf[(size_t)j * NVIS + k];
        for (int k = lane; k < NCOND; k += 64)
            s += (double)cd[(size_t)b * NCOND + k] * (double)BmTf[(size_t)j * NCOND + k];
        for (int m = 32; m; m >>= 1) s += __shfl_xor(s, m);
        if (lane == 0) {
            double z = s + (double)cvec[j];
            double mm = 1.0 / (1.0 + exp(-z));
            h[(size_t)b * NHID + j] =
                ((double)noise[(size_t)b * NHID + j] < mm) ? (unsigned char)1 : (unsigned char)0;
        }
    }
}

// ---------------- k3: merge 8 block-top2 per row; flag near-ties -----------
__global__ __launch_bounds__(256) void k3_merge8(
    const float4* __restrict__ blockbest, unsigned* __restrict__ rowbest,
    unsigned* __restrict__ rcnt, unsigned* __restrict__ rowflag) {
    const int t = threadIdx.x;
    const int row = blockIdx.x * 32 + (t >> 3), e = t & 7;
    float4 f = blockbest[(size_t)row * 8 + e];
    float best = f.x, sec = f.y;
    unsigned idx = __float_as_uint(f.z);
#pragma unroll
    for (int m = 1; m < 8; m <<= 1) {
        float ob = __shfl_xor(best, m);
        unsigned oi = __shfl_xor(idx, m);
        float os = __shfl_xor(sec, m);
        merge3(best, idx, sec, ob, oi, os);
    }
    if (e == 0) {
        rowbest[row] = idx;
        if (best - sec < 4e-3f) {
            unsigned p = atomicAdd(rcnt, 1u);
            if (p < 4096) rowflag[p] = (unsigned)row;
        }
    }
}

// ---------------- onehot write (all rows, fast-path argmax) ----------------
__global__ __launch_bounds__(256) void k_onehot(const unsigned* __restrict__ rowbest,
                                                float* __restrict__ out) {
    const int row = blockIdx.x;
    const unsigned idx = rowbest[row];
    const int base = threadIdx.x * 4;
    float4 o;
    o.x = (base + 0 == (int)idx) ? 1.f : 0.f;
    o.y = (base + 1 == (int)idx) ? 1.f : 0.f;
    o.z = (base + 2 == (int)idx) ? 1.f : 0.f;
    o.w = (base + 3 == (int)idx) ? 1.f : 0.f;
    *(float4*)(out + (size_t)row * NVIS + base) = o;
}

// ---------------- k6a: exact f64 pre for flagged rows (h u8) ---------------
__global__ __launch_bounds__(256) void k6_rows_pre(
    const unsigned char* __restrict__ h, const float* __restrict__ cd,
    const float* __restrict__ W, const float* __restrict__ ATf, const float* __restrict__ bvec,
    const unsigned* __restrict__ rcnt, const unsigned* __restrict__ rowflag,
    double* __restrict__ prebuf) {
    const int gw = (blockIdx.x * 256 + threadIdx.x) >> 6, lane = threadIdx.x & 63;
    const int nw = gridDim.x * 4;
    unsigned n = *rcnt; if (n > RCAP) n = RCAP;
    for (unsigned e = gw; e < n * 1024u; e += nw) {
        int ri = e >> 10, i = e & 1023;
        int b = (int)rowflag[ri];
        double s = 0.0;
        for (int k = lane; k < NHID; k += 64) {
            double hv = h[(size_t)b * NHID + k] ? 1.0 : 0.0;
            s += hv * (double)W[(size_t)i * NHID + k];
        }
        for (int k = lane; k < NCOND; k += 64)
            s += (double)cd[(size_t)b * NCOND + k] * (double)ATf[(size_t)i * NCOND + k];
        for (int m = 32; m; m >>= 1) s += __shfl_xor(s, m);
        if (lane == 0) prebuf[(size_t)ri * 1024 + i] = s + (double)bvec[i];
    }
}

// ---------------- k6b: exact argmax + rewrite flagged rows -----------------
__global__ __launch_bounds__(256) void k6_rows_argmax(
    const unsigned* __restrict__ rcnt, const unsigned* __restrict__ rowflag,
    const double* __restrict__ prebuf, float* __restrict__ out) {
    __shared__ double sv[256];
    __shared__ int si[256];
    unsigned n = *rcnt; if (n > RCAP) n = RCAP;
    const int t = threadIdx.x;
    for (unsigned ri = blockIdx.x; ri < n; ri += gridDim.x) {
        const int row = (int)rowflag[ri];
        const double* pr = prebuf + (size_t)ri * 1024;
        double best = pr[t * 4];
        int bi = t * 4;
#pragma unroll
        for (int e = 1; e < 4; ++e) {
            double v = pr[t * 4 + e];
            if (v > best) { best = v; bi = t * 4 + e; }
        }
        sv[t] = best; si[t] = bi;
        __syncthreads();
        for (int s = 128; s; s >>= 1) {
            if (t < s) {
                double v2 = sv[t + s]; int i2 = si[t + s];
                if (v2 > sv[t] || (v2 == sv[t] && i2 < si[t])) { sv[t] = v2; si[t] = i2; }
            }
            __syncthreads();
        }
        const int amax = si[0];
        const int base = t * 4;
        float4 o;
        o.x = (base + 0 == amax) ? 1.f : 0.f;
        o.y = (base + 1 == amax) ? 1.f : 0.f;
        o.z = (base + 2 == amax) ? 1.f : 0.f;
        o.w = (base + 3 == amax) ? 1.f : 0.f;
        *(float4*)(out + (size_t)row * NVIS + base) = o;
        __syncthreads();
    }
}

// ---------------- launch ----------------
extern "C" void kernel_launch(void* const* d_in, const int* in_sizes, int n_in,
                              void* d_out, int out_size, void* d_ws, size_t ws_size,
                              hipStream_t stream) {
    const float* vd = (const float*)d_in[0];  // [4096,1024]
    const float* cd = (const float*)d_in[1];  // [4096,512]
    const float* nz = (const float*)d_in[2];  // [4096,4096]
    const float* W  = (const float*)d_in[3];  // [1024,4096]
    const float* bv = (const float*)d_in[4];  // [1024]
    const float* cv = (const float*)d_in[5];  // [4096]
    const float* Am = (const float*)d_in[6];  // [512,1024]
    const float* Bm = (const float*)d_in[7];  // [512,4096]
    float* out = (float*)d_out;
    char* w = (char*)d_ws;

    unsigned short* WT0  = (unsigned short*)(w + F_WT0);
    unsigned short* WT1  = (unsigned short*)(w + F_WT1);
    unsigned short* BmT0 = (unsigned short*)(w + F_BMT0);
    unsigned short* BmT1 = (unsigned short*)(w + F_BMT1);
    unsigned short* AT0  = (unsigned short*)(w + F_AT0);
    unsigned short* AT1  = (unsigned short*)(w + F_AT1);
    unsigned short* V0   = (unsigned short*)(w + F_V0);
    unsigned short* V1   = (unsigned short*)(w + F_V1);
    unsigned short* U0   = (unsigned short*)(w + F_U0);
    unsigned short* U1   = (unsigned short*)(w + F_U1);
    signed char*    QH   = (signed char*)(w + F_QH);
    signed char*    QL   = (signed char*)(w + F_QL);
    float*          SINV = (float*)(w + F_SINV);
    unsigned char*  hbf  = (unsigned char*)(w + F_H);
    float4*   blockbest  = (float4*)(w + F_BB);
    unsigned* hflag      = (unsigned*)(w + F_HFLAG);
    unsigned* rowflag    = (unsigned*)(w + F_RFLAG);
    unsigned* rowbest    = (unsigned*)(w + F_RBEST);
    unsigned* counters   = (unsigned*)(w + F_CNT);
    double*   prebuf     = (double*)(w + F_PREB);
    unsigned* hcnt = &counters[0];
    unsigned* rcnt = &counters[1];
    float* WTf32  = (float*)(w + F_V0);    // 16MB (V region, dead after k1)
    float* BmTf32 = (float*)(w + F_WT0);   //  8MB (dead after k1)
    float* ATf32  = (float*)(w + F_WT1);   //  2MB (dead after k1)

    dim3 blk(256);
    kz_zero<<<1, 64, 0, stream>>>(counters);
    transpose_split<<<dim3(NHID / 32, NVIS / 32), blk, 0, stream>>>(W, NVIS, NHID, WT0, WT1);
    transpose_split<<<dim3(NHID / 32, NCOND / 32), blk, 0, stream>>>(Bm, NCOND, NHID, BmT0, BmT1);
    transpose_split<<<dim3(NVIS / 32, NCOND / 32), blk, 0, stream>>>(Am, NCOND, NVIS, AT0, AT1);
    split_planes<<<2048, blk, 0, stream>>>(vd, BATCH * NVIS / 4, V0, V1);
    split_planes<<<2048, blk, 0, stream>>>(cd, BATCH * NCOND / 4, U0, U1);
    quantize_w<<<NVIS, blk, 0, stream>>>(W, QH, QL, SINV);
    k1_t2<<<dim3(NHID / 256, BATCH / 256), 512, 0, stream>>>(
        nz, V0, V1, U0, U1, WT0, WT1, BmT0, BmT1, cv, hbf, hcnt, hflag);
    transpose_f32_all<<<6656, blk, 0, stream>>>(W, Bm, Am, WTf32, BmTf32, ATf32);
    k5_recheck_h<<<256, blk, 0, stream>>>(vd, cd, nz, WTf32, BmTf32, cv, hcnt, hflag, hbf);
    k2_i8<<<dim3(NVIS / 128, BATCH / 128), 512, 0, stream>>>(
        hbf, U0, U1, QH, QL, SINV, AT0, AT1, bv, blockbest);
    k3_merge8<<<BATCH / 32, blk, 0, stream>>>(blockbest, rowbest, rcnt, rowflag);
    k_onehot<<<BATCH, blk, 0, stream>>>(rowbest, out);
    k6_rows_pre<<<512, blk, 0, stream>>>(hbf, cd, W, ATf32, bv, rcnt, rowflag, prebuf);
    k6_rows_argmax<<<64, blk, 0, stream>>>(rcnt, rowflag, prebuf, out);
}

// Round 15
// 498.795 us; speedup vs baseline: 1.1514x; 1.0602x over previous
//
#include <hip/hip_runtime.h>
#include <math.h>

static constexpr int BATCH = 4096;
static constexpr int NVIS  = 1024;
static constexpr int NHID  = 4096;
static constexpr int NCOND = 512;

typedef __attribute__((ext_vector_type(8))) short bf16x8;
typedef __attribute__((ext_vector_type(4))) float f32x4;
typedef __attribute__((ext_vector_type(4))) int   i32x4;

static constexpr unsigned HCAP = 131072;
static constexpr unsigned RCAP = 256;
static constexpr size_t MB = 1u << 20;

// ---------------- ws layout (proven) ----------------
static constexpr size_t F_WT0   = 0;                 // W^T bf16 planes (dead after k1)
static constexpr size_t F_WT1   = F_WT0  + 8*MB;
static constexpr size_t F_BMT0  = F_WT1  + 8*MB;
static constexpr size_t F_BMT1  = F_BMT0 + 4*MB;
static constexpr size_t F_AT0   = F_BMT1 + 4*MB;
static constexpr size_t F_AT1   = F_AT0  + 1*MB;
static constexpr size_t F_V0    = F_AT1  + 1*MB;     // vd planes (dead after k1 -> WTf32)
static constexpr size_t F_V1    = F_V0   + 8*MB;
static constexpr size_t F_U0    = F_V1   + 8*MB;
static constexpr size_t F_U1    = F_U0   + 4*MB;
static constexpr size_t F_QH    = F_U1   + 4*MB;     // W i8 hi plane [1024][4096]
static constexpr size_t F_QL    = F_QH   + 4*MB;     // W i8 lo plane
static constexpr size_t F_SINV  = F_QL   + 4*MB;     // f32[1024]
static constexpr size_t F_H     = F_SINV + 8*MB;     // h u8 [4096][4096]
static constexpr size_t F_BB    = F_H    + 32*MB;    // blockbest [4096][8] float4
static constexpr size_t F_HFLAG = F_BB   + 1*MB;
static constexpr size_t F_RFLAG = F_HFLAG + 512*1024;
static constexpr size_t F_RBEST = F_RFLAG + 16384;
static constexpr size_t F_CNT   = F_RBEST + 16384;
static constexpr size_t F_PREB  = F_CNT  + 256;
static constexpr size_t WS_FULL = F_PREB + 2*MB;

// ---------------- helpers ----------------
__device__ __forceinline__ void gload16(const void* g, void* l) {
    __builtin_amdgcn_global_load_lds(
        (const __attribute__((address_space(1))) void*)g,
        (__attribute__((address_space(3))) void*)l, 16, 0, 0);
}

__device__ __forceinline__ void split1(float x, unsigned short& hi, unsigned short& lo) {
    unsigned u = __float_as_uint(x);
    unsigned r = u + 0x7FFFu + ((u >> 16) & 1u);      // RN-even f32->bf16
    hi = (unsigned short)(r >> 16);
    float rem = x - __uint_as_float(r & 0xFFFF0000u); // exact (Sterbenz)
    unsigned u2 = __float_as_uint(rem);
    unsigned r2 = u2 + 0x7FFFu + ((u2 >> 16) & 1u);
    lo = (unsigned short)(r2 >> 16);
}

__device__ __forceinline__ void merge3(float& b, unsigned& ix, float& s,
                                       float b2, unsigned i2, float s2) {
    if (b2 > b || (b2 == b && i2 < ix)) { s = fmaxf(b, s2); b = b2; ix = i2; }
    else                                { s = fmaxf(s, b2); }
}

// ---------------- prep kernels ----------------
__global__ void kz_zero(unsigned* c) { if (threadIdx.x < 64) c[threadIdx.x] = 0; }

// fused transpose+split for W, Bm, Am (one launch; proven body, block-decode)
__global__ __launch_bounds__(256) void transpose_split_all(
    const float* __restrict__ W, const float* __restrict__ Bm, const float* __restrict__ Am,
    unsigned short* __restrict__ WT0, unsigned short* __restrict__ WT1,
    unsigned short* __restrict__ BmT0, unsigned short* __restrict__ BmT1,
    unsigned short* __restrict__ AT0, unsigned short* __restrict__ AT1) {
    __shared__ float tile[32][33];
    int blk = blockIdx.x;
    const float* src; unsigned short *d0, *d1; int R, C, bx, by;
    if (blk < 4096)      { src = W;  d0 = WT0;  d1 = WT1;  R = 1024; C = 4096; bx = blk & 127; by = blk >> 7; }
    else if (blk < 6144) { src = Bm; d0 = BmT0; d1 = BmT1; R = 512;  C = 4096; blk -= 4096; bx = blk & 127; by = blk >> 7; }
    else                 { src = Am; d0 = AT0;  d1 = AT1;  R = 512;  C = 1024; blk -= 6144; bx = blk & 31;  by = blk >> 5; }
    const int c0 = bx * 32, r0 = by * 32;
    const int tx = threadIdx.x & 31, ty = threadIdx.x >> 5;
#pragma unroll
    for (int e = 0; e < 4; ++e)
        tile[ty + e * 8][tx] = src[(size_t)(r0 + ty + e * 8) * C + c0 + tx];
    __syncthreads();
#pragma unroll
    for (int e = 0; e < 4; ++e) {
        int c = c0 + ty + e * 8;
        unsigned short hi, lo;
        split1(tile[tx][ty + e * 8], hi, lo);
        d0[(size_t)c * R + r0 + tx] = hi;
        d1[(size_t)c * R + r0 + tx] = lo;
    }
}

// fused elementwise split for vd and cd (one launch)
__global__ __launch_bounds__(256) void split_planes_all(
    const float* __restrict__ vd, const float* __restrict__ cd,
    unsigned short* __restrict__ V0, unsigned short* __restrict__ V1,
    unsigned short* __restrict__ U0, unsigned short* __restrict__ U1) {
    const int n4v = BATCH * NVIS / 4;                 // 1048576
    const int n4t = n4v + BATCH * NCOND / 4;          // 1572864
    for (int i = blockIdx.x * 256 + threadIdx.x; i < n4t; i += gridDim.x * 256) {
        const float4 v = (i < n4v) ? ((const float4*)vd)[i] : ((const float4*)cd)[i - n4v];
        unsigned short h0,h1,h2,h3,l0,l1,l2,l3;
        split1(v.x,h0,l0); split1(v.y,h1,l1); split1(v.z,h2,l2); split1(v.w,h3,l3);
        if (i < n4v) {
            ((ushort4*)V0)[i] = make_ushort4(h0,h1,h2,h3);
            ((ushort4*)V1)[i] = make_ushort4(l0,l1,l2,l3);
        } else {
            ((ushort4*)U0)[i - n4v] = make_ushort4(h0,h1,h2,h3);
            ((ushort4*)U1)[i - n4v] = make_ushort4(l0,l1,l2,l3);
        }
    }
}

// fused f32 transposes: W->WTf, Bm->BmTf, Am->ATf (after k1; proven)
__global__ __launch_bounds__(256) void transpose_f32_all(
    const float* __restrict__ W, const float* __restrict__ Bm, const float* __restrict__ Am,
    float* __restrict__ WTf, float* __restrict__ BmTf, float* __restrict__ ATf) {
    __shared__ float tile[32][33];
    int blk = blockIdx.x;
    const float* src; float* dst; int R, C, bx, by;
    if (blk < 4096)      { src = W;  dst = WTf;  R = 1024; C = 4096; bx = blk & 127; by = blk >> 7; }
    else if (blk < 6144) { src = Bm; dst = BmTf; R = 512;  C = 4096; blk -= 4096; bx = blk & 127; by = blk >> 7; }
    else                 { src = Am; dst = ATf;  R = 512;  C = 1024; blk -= 6144; bx = blk & 31;  by = blk >> 5; }
    const int c0 = bx * 32, r0 = by * 32;
    const int tx = threadIdx.x & 31, ty = threadIdx.x >> 5;
#pragma unroll
    for (int e = 0; e < 4; ++e)
        tile[ty + e * 8][tx] = src[(size_t)(r0 + ty + e * 8) * C + c0 + tx];
    __syncthreads();
#pragma unroll
    for (int e = 0; e < 4; ++e)
        dst[(size_t)(c0 + ty + e * 8) * R + r0 + tx] = tile[tx][ty + e * 8];
}

// W rows -> 15-bit fixed point (2 i8 planes + per-row inverse scale)
__global__ __launch_bounds__(256) void quantize_w(
    const float* __restrict__ W, signed char* __restrict__ QH,
    signed char* __restrict__ QL, float* __restrict__ SINV) {
    __shared__ float red[256];
    const int i = blockIdx.x, t = threadIdx.x;
    const float* row = W + (size_t)i * NHID;
    float4 v[4];
    float mx = 0.f;
#pragma unroll
    for (int e = 0; e < 4; ++e) {
        v[e] = *(const float4*)(row + e * 1024 + t * 4);
        mx = fmaxf(mx, fmaxf(fmaxf(fabsf(v[e].x), fabsf(v[e].y)),
                             fmaxf(fabsf(v[e].z), fabsf(v[e].w))));
    }
    red[t] = mx; __syncthreads();
    for (int s = 128; s; s >>= 1) {
        if (t < s) red[t] = fmaxf(red[t], red[t + s]);
        __syncthreads();
    }
    const float rm = fmaxf(red[0], 1e-30f);
    const float sc = 32256.f / rm;
    if (t == 0) SINV[i] = rm / 32256.f;
#pragma unroll
    for (int e = 0; e < 4; ++e) {
        const float* pv = (const float*)&v[e];
        unsigned ph = 0, pl = 0;
#pragma unroll
        for (int j = 0; j < 4; ++j) {
            int wq = (int)lrintf(pv[j] * sc);
            int hi = (wq + 128) >> 8;
            int lo = wq - (hi << 8);
            ph |= ((unsigned)hi & 0xFFu) << (8 * j);
            pl |= ((unsigned)lo & 0xFFu) << (8 * j);
        }
        *(unsigned*)(QH + (size_t)i * NHID + e * 1024 + t * 4) = ph;
        *(unsigned*)(QL + (size_t)i * NHID + e * 1024 + t * 4) = pl;
    }
}

// ===========================================================================
// k1_b64: round-12 kernel VERBATIM (best k1 measured: 233us).
// 256x256 tile, BK=64, 24 K-steps, single 128KB buffer, serial
// stage->sync->compute, 3-bit chunk-XOR swizzle, XCD-aware block swizzle.
// ===========================================================================
__global__ __launch_bounds__(512, 1) void k1_b64(
    const float* __restrict__ noise,
    const unsigned short* __restrict__ V0, const unsigned short* __restrict__ V1,
    const unsigned short* __restrict__ U0, const unsigned short* __restrict__ U1,
    const unsigned short* __restrict__ WT0, const unsigned short* __restrict__ WT1,
    const unsigned short* __restrict__ BmT0, const unsigned short* __restrict__ BmT1,
    const float* __restrict__ cvec, unsigned char* __restrict__ hout,
    unsigned* __restrict__ hcnt, unsigned* __restrict__ hflag)
{
    __shared__ __align__(16) unsigned short As0[256][64], As1[256][64],
                                            Bs0[256][64], Bs1[256][64];
    const int t = threadIdx.x, lane = t & 63, wid = t >> 6;
    const int g = lane >> 4, cc = lane & 15;
    const int wrow = wid >> 2, wcol = wid & 3;      // 2M x 4N waves
    const int nwg = gridDim.x * gridDim.y;
    const int bid = blockIdx.y * gridDim.x + blockIdx.x;
    const int q = nwg >> 3;
    const int swz = (bid & 7) * q + (bid >> 3);
    const int b0 = (swz / gridDim.x) * 256;
    const int j0 = (swz % gridDim.x) * 256;

    f32x4 acc[8][4] = {};
    bf16x8 a0q[4], a1q[4];
    bf16x8 b0a[2][2], b1a[2][2];

    auto lba = [&](int r, int kk) {
        return (size_t)r * 128 + (size_t)(((kk << 2) | g) ^ (r & 7)) * 16;
    };
    auto readA = [&](int mh, int kk) {
#pragma unroll
        for (int k = 0; k < 4; ++k) {
            int r = wrow * 128 + (4 * mh + k) * 16 + cc;
            a0q[k] = *(const bf16x8*)((const char*)As0 + lba(r, kk));
            a1q[k] = *(const bf16x8*)((const char*)As1 + lba(r, kk));
        }
    };
    auto readB = [&](int nh, int kk) {
#pragma unroll
        for (int k = 0; k < 2; ++k) {
            int n = wcol * 64 + (2 * nh + k) * 16 + cc;
            b0a[nh][k] = *(const bf16x8*)((const char*)Bs0 + lba(n, kk));
            b1a[nh][k] = *(const bf16x8*)((const char*)Bs1 + lba(n, kk));
        }
    };
    auto mfma24 = [&](int mh, int nh) {
#pragma unroll
        for (int k = 0; k < 4; ++k)
#pragma unroll
            for (int n = 0; n < 2; ++n) {
                f32x4 c = acc[4 * mh + k][2 * nh + n];
                c = __builtin_amdgcn_mfma_f32_16x16x32_bf16(a0q[k], b0a[nh][n], c, 0, 0, 0);
                c = __builtin_amdgcn_mfma_f32_16x16x32_bf16(a0q[k], b1a[nh][n], c, 0, 0, 0);
                c = __builtin_amdgcn_mfma_f32_16x16x32_bf16(a1q[k], b0a[nh][n], c, 0, 0, 0);
                acc[4 * mh + k][2 * nh + n] = c;
            }
    };

    for (int tt = 0; tt < 24; ++tt) {
        const unsigned short *A0_, *A1_, *B0_, *B1_; int K_, k0_;
        if (tt < 16) { A0_ = V0; A1_ = V1; B0_ = WT0; B1_ = WT1; K_ = 1024; k0_ = tt * 64; }
        else         { A0_ = U0; A1_ = U1; B0_ = BmT0; B1_ = BmT1; K_ = 512; k0_ = (tt - 16) * 64; }
        __syncthreads();   // WAR: previous step's reads done before overwrite
#pragma unroll
        for (int e = 0; e < 4; ++e) {
            int idx = t + e * 512;
            int r = idx >> 3, p = idx & 7;
            int s = p ^ (r & 7);            // pre-swizzled source chunk
            size_t ga = (size_t)(b0 + r) * K_ + k0_ + s * 8;
            size_t gb = (size_t)(j0 + r) * K_ + k0_ + s * 8;
            size_t ldd = (size_t)idx * 16;  // bytes
            gload16(A0_ + ga, (char*)As0 + ldd);
            gload16(A1_ + ga, (char*)As1 + ldd);
            gload16(B0_ + gb, (char*)Bs0 + ldd);
            gload16(B1_ + gb, (char*)Bs1 + ldd);
        }
        __syncthreads();   // drains vmcnt: tile visible
#pragma unroll
        for (int kk = 0; kk < 2; ++kk) {
            readA(0, kk); readB(0, kk);
            __builtin_amdgcn_s_setprio(1); mfma24(0, 0); __builtin_amdgcn_s_setprio(0);
            readB(1, kk);
            __builtin_amdgcn_s_setprio(1); mfma24(0, 1); __builtin_amdgcn_s_setprio(0);
            readA(1, kk);
            __builtin_amdgcn_s_setprio(1); mfma24(1, 0); mfma24(1, 1); __builtin_amdgcn_s_setprio(0);
        }
    }

#pragma unroll
    for (int ni = 0; ni < 4; ++ni) {
        int j = j0 + wcol * 64 + ni * 16 + cc;
        float cj = cvec[j];
#pragma unroll
        for (int mi = 0; mi < 8; ++mi) {
#pragma unroll
            for (int i = 0; i < 4; ++i) {
                int b = b0 + wrow * 128 + mi * 16 + g * 4 + i;
                float z = acc[mi][ni][i] + cj;
                float m = 1.0f / (1.0f + __expf(-z));
                float nv = noise[(size_t)b * NHID + j];
                hout[(size_t)b * NHID + j] = (nv < m) ? (unsigned char)1 : (unsigned char)0;
                if (fabsf(nv - m) < 2.5e-4f) {
                    unsigned p = atomicAdd(hcnt, 1u);
                    if (p < HCAP) hflag[p] = ((unsigned)b << 12) | (unsigned)j;
                }
            }
        }
    }
}

// ===========================================================================
// k2_i8: (round-11/12 kernel, unchanged)
// ===========================================================================
__global__ __launch_bounds__(512, 2) void k2_i8(
    const unsigned char* __restrict__ hbf,
    const unsigned short* __restrict__ U0, const unsigned short* __restrict__ U1,
    const signed char* __restrict__ QH, const signed char* __restrict__ QL,
    const float* __restrict__ SINV,
    const unsigned short* __restrict__ AT0, const unsigned short* __restrict__ AT1,
    const float* __restrict__ bvec, float4* __restrict__ blockbest)
{
    __shared__ __align__(16) char smem[32768];
    __shared__ float4 mbuf[4][128];
    const int t = threadIdx.x, lane = t & 63, wid = t >> 6;
    const int g = lane >> 4, cc = lane & 15;
    const int wrow = wid >> 2, wcol = wid & 3;
    const int pcb = (g ^ ((cc >> 1) & 3)) * 16;
    const int nwg = gridDim.x * gridDim.y;
    const int bid = blockIdx.y * gridDim.x + blockIdx.x;
    const int q = nwg >> 3;
    const int swz = (bid & 7) * q + (bid >> 3);
    const int b0 = (swz / gridDim.x) * 128;
    const int i0 = (swz % gridDim.x) * 128;

    char* Ah  = smem;
    char* Qhs = smem + 8192;
    char* Qls = smem + 16384;

    i32x4 ah[4][2] = {}, al[4][2] = {};

    for (int k0 = 0; k0 < NHID; k0 += 64) {
        __syncthreads();
        {
            int r = t >> 2, s = t & 3, sc = s ^ ((r >> 1) & 3);
            size_t off = (size_t)r * 64 + s * 16;
            gload16(hbf + (size_t)(b0 + r) * NHID + k0 + sc * 16, Ah + off);
            gload16(QH + (size_t)(i0 + r) * NHID + k0 + sc * 16, Qhs + off);
            gload16(QL + (size_t)(i0 + r) * NHID + k0 + sc * 16, Qls + off);
        }
        __syncthreads();
        i32x4 bh[2], bl[2];
#pragma unroll
        for (int ni = 0; ni < 2; ++ni) {
            int n = wcol * 32 + ni * 16 + cc;
            bh[ni] = *(const i32x4*)(Qhs + (size_t)n * 64 + pcb);
            bl[ni] = *(const i32x4*)(Qls + (size_t)n * 64 + pcb);
        }
#pragma unroll
        for (int mi = 0; mi < 4; ++mi) {
            i32x4 a = *(const i32x4*)(Ah + (size_t)(wrow * 64 + mi * 16 + cc) * 64 + pcb);
#pragma unroll
            for (int ni = 0; ni < 2; ++ni) {
                ah[mi][ni] = __builtin_amdgcn_mfma_i32_16x16x64_i8(a, bh[ni], ah[mi][ni], 0, 0, 0);
                al[mi][ni] = __builtin_amdgcn_mfma_i32_16x16x64_i8(a, bl[ni], al[mi][ni], 0, 0, 0);
            }
        }
    }
    f32x4 acc[4][2];
#pragma unroll
    for (int ni = 0; ni < 2; ++ni) {
        int col = i0 + wcol * 32 + ni * 16 + cc;
        float sv = SINV[col];
#pragma unroll
        for (int mi = 0; mi < 4; ++mi)
#pragma unroll
            for (int e = 0; e < 4; ++e)
                acc[mi][ni][e] = fmaf(256.f, (float)ah[mi][ni][e], (float)al[mi][ni][e]) * sv;
    }

    char* As0 = smem;
    char* As1 = smem + 8192;
    char* Bs0 = smem + 16384;
    char* Bs1 = smem + 24576;
    for (int k0 = 0; k0 < NCOND; k0 += 32) {
        __syncthreads();
        {
            int r = t >> 2, s = t & 3, sc = s ^ ((r >> 1) & 3);
            size_t off = (size_t)r * 64 + s * 16;
            size_t ga = (size_t)(b0 + r) * NCOND + k0 + sc * 8;
            gload16(U0 + ga, As0 + off);
            gload16(U1 + ga, As1 + off);
            size_t go = (size_t)(i0 + r) * NCOND + k0 + sc * 8;
            gload16(AT0 + go, Bs0 + off);
            gload16(AT1 + go, Bs1 + off);
        }
        __syncthreads();
        bf16x8 bb0[2], bb1[2];
#pragma unroll
        for (int ni = 0; ni < 2; ++ni) {
            int n = wcol * 32 + ni * 16 + cc;
            bb0[ni] = *(const bf16x8*)(Bs0 + (size_t)n * 64 + pcb);
            bb1[ni] = *(const bf16x8*)(Bs1 + (size_t)n * 64 + pcb);
        }
#pragma unroll
        for (int mi = 0; mi < 4; ++mi) {
            int r = wrow * 64 + mi * 16 + cc;
            bf16x8 a0 = *(const bf16x8*)(As0 + (size_t)r * 64 + pcb);
            bf16x8 a1 = *(const bf16x8*)(As1 + (size_t)r * 64 + pcb);
#pragma unroll
            for (int ni = 0; ni < 2; ++ni) {
                acc[mi][ni] = __builtin_amdgcn_mfma_f32_16x16x32_bf16(a0, bb0[ni], acc[mi][ni], 0, 0, 0);
                acc[mi][ni] = __builtin_amdgcn_mfma_f32_16x16x32_bf16(a0, bb1[ni], acc[mi][ni], 0, 0, 0);
                acc[mi][ni] = __builtin_amdgcn_mfma_f32_16x16x32_bf16(a1, bb0[ni], acc[mi][ni], 0, 0, 0);
            }
        }
    }

#pragma unroll
    for (int ni = 0; ni < 2; ++ni) {
        int colb = i0 + wcol * 32 + ni * 16 + cc;
        float bb = bvec[colb];
#pragma unroll
        for (int mi = 0; mi < 4; ++mi)
#pragma unroll
            for (int i = 0; i < 4; ++i) acc[mi][ni][i] += bb;
    }
#pragma unroll
    for (int mi = 0; mi < 4; ++mi) {
#pragma unroll
        for (int i = 0; i < 4; ++i) {
            float best = acc[mi][0][i];
            unsigned bidx = (unsigned)(i0 + wcol * 32 + cc);
            float sec = -3.4e38f;
            merge3(best, bidx, sec, acc[mi][1][i],
                   (unsigned)(i0 + wcol * 32 + 16 + cc), -3.4e38f);
#pragma unroll
            for (int m = 1; m < 16; m <<= 1) {
                float ob = __shfl_xor(best, m);
                unsigned oi = __shfl_xor(bidx, m);
                float os = __shfl_xor(sec, m);
                merge3(best, bidx, sec, ob, oi, os);
            }
            if (cc == 0)
                mbuf[wcol][wrow * 64 + mi * 16 + g * 4 + i] =
                    make_float4(best, sec, __uint_as_float(bidx), 0.f);
        }
    }
    __syncthreads();
    if (t < 128) {
        float4 f0 = mbuf[0][t];
        float best = f0.x, sec = f0.y;
        unsigned bidx = __float_as_uint(f0.z);
#pragma unroll
        for (int wq = 1; wq < 4; ++wq) {
            float4 fq = mbuf[wq][t];
            merge3(best, bidx, sec, fq.x, __float_as_uint(fq.z), fq.y);
        }
        blockbest[(size_t)(b0 + t) * 8 + (unsigned)(i0 >> 7)] =
            make_float4(best, sec, __uint_as_float(bidx), 0.f);
    }
}

// ---------------- k5: exact f64 recheck, coalesced (h u8) -------------------
__global__ __launch_bounds__(256) void k5_recheck_h(
    const float* __restrict__ vd, const float* __restrict__ cd, const float* __restrict__ noise,
    const float* __restrict__ WTf, const float* __restrict__ BmTf, const float* __restrict__ cvec,
    const unsigned* __restrict__ hcnt, const unsigned* __restrict__ hflag,
    unsigned char* __restrict__ h) {
    const int gw = (blockIdx.x * 256 + threadIdx.x) >> 6, lane = threadIdx.x & 63;
    const int nw = gridDim.x * 4;
    unsigned n = *hcnt; if (n > HCAP) n = HCAP;
    for (unsigned e = gw; e < n; e += nw) {
        unsigned p = hflag[e];
        int b = p >> 12, j = p & 4095;
        double s = 0.0;
        for (int k = lane; k < NVIS; k += 64)
            s += (double)vd[(size_t)b * NVIS + k] * (double)WTf[(size_t)j * NVIS + k];
        for (int k = lane; k < NCOND; k += 64)
            s += (double)cd[(size_t)b * NCOND + k] * (double)BmTf[(size_t)j * NCOND + k];
        for (int m = 32; m; m >>= 1) s += __shfl_xor(s, m);
        if (lane == 0) {
            double z = s + (double)cvec[j];
            double mm = 1.0 / (1.0 + exp(-z));
            h[(size_t)b * NHID + j] =
                ((double)noise[(size_t)b * NHID + j] < mm) ? (unsigned char)1 : (unsigned char)0;
        }
    }
}

// ---------------- k3: merge 8 block-top2 per row; flag near-ties -----------
__global__ __launch_bounds__(256) void k3_merge8(
    const float4* __restrict__ blockbest, unsigned* __restrict__ rowbest,
    unsigned* __restrict__ rcnt, unsigned* __restrict__ rowflag) {
    const int t = threadIdx.x;
    const int row = blockIdx.x * 32 + (t >> 3), e = t & 7;
    float4 f = blockbest[(size_t)row * 8 + e];
    float best = f.x, sec = f.y;
    unsigned idx = __float_as_uint(f.z);
#pragma unroll
    for (int m = 1; m < 8; m <<= 1) {
        float ob = __shfl_xor(best, m);
        unsigned oi = __shfl_xor(idx, m);
        float os = __shfl_xor(sec, m);
        merge3(best, idx, sec, ob, oi, os);
    }
    if (e == 0) {
        rowbest[row] = idx;
        if (best - sec < 4e-3f) {
            unsigned p = atomicAdd(rcnt, 1u);
            if (p < 4096) rowflag[p] = (unsigned)row;
        }
    }
}

// ---------------- onehot write (all rows, fast-path argmax) ----------------
__global__ __launch_bounds__(256) void k_onehot(const unsigned* __restrict__ rowbest,
                                                float* __restrict__ out) {
    const int row = blockIdx.x;
    const unsigned idx = rowbest[row];
    const int base = threadIdx.x * 4;
    float4 o;
    o.x = (base + 0 == (int)idx) ? 1.f : 0.f;
    o.y = (base + 1 == (int)idx) ? 1.f : 0.f;
    o.z = (base + 2 == (int)idx) ? 1.f : 0.f;
    o.w = (base + 3 == (int)idx) ? 1.f : 0.f;
    *(float4*)(out + (size_t)row * NVIS + base) = o;
}

// ---------------- k6a: exact f64 pre for flagged rows (h u8) ---------------
__global__ __launch_bounds__(256) void k6_rows_pre(
    const unsigned char* __restrict__ h, const float* __restrict__ cd,
    const float* __restrict__ W, const float* __restrict__ ATf, const float* __restrict__ bvec,
    const unsigned* __restrict__ rcnt, const unsigned* __restrict__ rowflag,
    double* __restrict__ prebuf) {
    const int gw = (blockIdx.x * 256 + threadIdx.x) >> 6, lane = threadIdx.x & 63;
    const int nw = gridDim.x * 4;
    unsigned n = *rcnt; if (n > RCAP) n = RCAP;
    for (unsigned e = gw; e < n * 1024u; e += nw) {
        int ri = e >> 10, i = e & 1023;
        int b = (int)rowflag[ri];
        double s = 0.0;
        for (int k = lane; k < NHID; k += 64) {
            double hv = h[(size_t)b * NHID + k] ? 1.0 : 0.0;
            s += hv * (double)W[(size_t)i * NHID + k];
        }
        for (int k = lane; k < NCOND; k += 64)
            s += (double)cd[(size_t)b * NCOND + k] * (double)ATf[(size_t)i * NCOND + k];
        for (int m = 32; m; m >>= 1) s += __shfl_xor(s, m);
        if (lane == 0) prebuf[(size_t)ri * 1024 + i] = s + (double)bvec[i];
    }
}

// ---------------- k6b: exact argmax + rewrite flagged rows -----------------
__global__ __launch_bounds__(256) void k6_rows_argmax(
    const unsigned* __restrict__ rcnt, const unsigned* __restrict__ rowflag,
    const double* __restrict__ prebuf, float* __restrict__ out) {
    __shared__ double sv[256];
    __shared__ int si[256];
    unsigned n = *rcnt; if (n > RCAP) n = RCAP;
    const int t = threadIdx.x;
    for (unsigned ri = blockIdx.x; ri < n; ri += gridDim.x) {
        const int row = (int)rowflag[ri];
        const double* pr = prebuf + (size_t)ri * 1024;
        double best = pr[t * 4];
        int bi = t * 4;
#pragma unroll
        for (int e = 1; e < 4; ++e) {
            double v = pr[t * 4 + e];
            if (v > best) { best = v; bi = t * 4 + e; }
        }
        sv[t] = best; si[t] = bi;
        __syncthreads();
        for (int s = 128; s; s >>= 1) {
            if (t < s) {
                double v2 = sv[t + s]; int i2 = si[t + s];
                if (v2 > sv[t] || (v2 == sv[t] && i2 < si[t])) { sv[t] = v2; si[t] = i2; }
            }
            __syncthreads();
        }
        const int amax = si[0];
        const int base = t * 4;
        float4 o;
        o.x = (base + 0 == amax) ? 1.f : 0.f;
        o.y = (base + 1 == amax) ? 1.f : 0.f;
        o.z = (base + 2 == amax) ? 1.f : 0.f;
        o.w = (base + 3 == amax) ? 1.f : 0.f;
        *(float4*)(out + (size_t)row * NVIS + base) = o;
        __syncthreads();
    }
}

// ---------------- launch ----------------
extern "C" void kernel_launch(void* const* d_in, const int* in_sizes, int n_in,
                              void* d_out, int out_size, void* d_ws, size_t ws_size,
                              hipStream_t stream) {
    const float* vd = (const float*)d_in[0];  // [4096,1024]
    const float* cd = (const float*)d_in[1];  // [4096,512]
    const float* nz = (const float*)d_in[2];  // [4096,4096]
    const float* W  = (const float*)d_in[3];  // [1024,4096]
    const float* bv = (const float*)d_in[4];  // [1024]
    const float* cv = (const float*)d_in[5];  // [4096]
    const float* Am = (const float*)d_in[6];  // [512,1024]
    const float* Bm = (const float*)d_in[7];  // [512,4096]
    float* out = (float*)d_out;
    char* w = (char*)d_ws;

    unsigned short* WT0  = (unsigned short*)(w + F_WT0);
    unsigned short* WT1  = (unsigned short*)(w + F_WT1);
    unsigned short* BmT0 = (unsigned short*)(w + F_BMT0);
    unsigned short* BmT1 = (unsigned short*)(w + F_BMT1);
    unsigned short* AT0  = (unsigned short*)(w + F_AT0);
    unsigned short* AT1  = (unsigned short*)(w + F_AT1);
    unsigned short* V0   = (unsigned short*)(w + F_V0);
    unsigned short* V1   = (unsigned short*)(w + F_V1);
    unsigned short* U0   = (unsigned short*)(w + F_U0);
    unsigned short* U1   = (unsigned short*)(w + F_U1);
    signed char*    QH   = (signed char*)(w + F_QH);
    signed char*    QL   = (signed char*)(w + F_QL);
    float*          SINV = (float*)(w + F_SINV);
    unsigned char*  hbf  = (unsigned char*)(w + F_H);
    float4*   blockbest  = (float4*)(w + F_BB);
    unsigned* hflag      = (unsigned*)(w + F_HFLAG);
    unsigned* rowflag    = (unsigned*)(w + F_RFLAG);
    unsigned* rowbest    = (unsigned*)(w + F_RBEST);
    unsigned* counters   = (unsigned*)(w + F_CNT);
    double*   prebuf     = (double*)(w + F_PREB);
    unsigned* hcnt = &counters[0];
    unsigned* rcnt = &counters[1];
    float* WTf32  = (float*)(w + F_V0);    // 16MB (V region, dead after k1)
    float* BmTf32 = (float*)(w + F_WT0);   //  8MB (dead after k1)
    float* ATf32  = (float*)(w + F_WT1);   //  2MB (dead after k1)

    dim3 blk(256);
    kz_zero<<<1, 64, 0, stream>>>(counters);
    transpose_split_all<<<6656, blk, 0, stream>>>(W, Bm, Am, WT0, WT1, BmT0, BmT1, AT0, AT1);
    split_planes_all<<<2048, blk, 0, stream>>>(vd, cd, V0, V1, U0, U1);
    quantize_w<<<NVIS, blk, 0, stream>>>(W, QH, QL, SINV);
    k1_b64<<<dim3(NHID / 256, BATCH / 256), 512, 0, stream>>>(
        nz, V0, V1, U0, U1, WT0, WT1, BmT0, BmT1, cv, hbf, hcnt, hflag);
    transpose_f32_all<<<6656, blk, 0, stream>>>(W, Bm, Am, WTf32, BmTf32, ATf32);
    k5_recheck_h<<<256, blk, 0, stream>>>(vd, cd, nz, WTf32, BmTf32, cv, hcnt, hflag, hbf);
    k2_i8<<<dim3(NVIS / 128, BATCH / 128), 512, 0, stream>>>(
        hbf, U0, U1, QH, QL, SINV, AT0, AT1, bv, blockbest);
    k3_merge8<<<BATCH / 32, blk, 0, stream>>>(blockbest, rowbest, rcnt, rowflag);
    k_onehot<<<BATCH, blk, 0, stream>>>(rowbest, out);
    k6_rows_pre<<<512, blk, 0, stream>>>(hbf, cd, W, ATf32, bv, rcnt, rowflag, prebuf);
    k6_rows_argmax<<<64, blk, 0, stream>>>(rcnt, rowflag, prebuf, out);
}

// Round 16
// 496.291 us; speedup vs baseline: 1.1572x; 1.0050x over previous
//
#include <hip/hip_runtime.h>
#include <math.h>

static constexpr int BATCH = 4096;
static constexpr int NVIS  = 1024;
static constexpr int NHID  = 4096;
static constexpr int NCOND = 512;

typedef __attribute__((ext_vector_type(8))) short bf16x8;
typedef __attribute__((ext_vector_type(4))) float f32x4;
typedef __attribute__((ext_vector_type(4))) int   i32x4;

static constexpr unsigned HCAP = 131072;
static constexpr unsigned RCAP = 256;
static constexpr size_t MB = 1u << 20;

// ---------------- ws layout (proven) ----------------
static constexpr size_t F_WT0   = 0;                 // W^T bf16 planes (dead after k1)
static constexpr size_t F_WT1   = F_WT0  + 8*MB;
static constexpr size_t F_BMT0  = F_WT1  + 8*MB;
static constexpr size_t F_BMT1  = F_BMT0 + 4*MB;
static constexpr size_t F_AT0   = F_BMT1 + 4*MB;
static constexpr size_t F_AT1   = F_AT0  + 1*MB;
static constexpr size_t F_V0    = F_AT1  + 1*MB;     // vd planes (dead after k1 -> WTf32)
static constexpr size_t F_V1    = F_V0   + 8*MB;
static constexpr size_t F_U0    = F_V1   + 8*MB;
static constexpr size_t F_U1    = F_U0   + 4*MB;
static constexpr size_t F_QH    = F_U1   + 4*MB;     // W i8 hi plane [1024][4096]
static constexpr size_t F_QL    = F_QH   + 4*MB;     // W i8 lo plane
static constexpr size_t F_SINV  = F_QL   + 4*MB;     // f32[1024]
static constexpr size_t F_H     = F_SINV + 8*MB;     // h u8 [4096][4096]
static constexpr size_t F_BB    = F_H    + 32*MB;    // blockbest [4096][8] float4
static constexpr size_t F_HFLAG = F_BB   + 1*MB;
static constexpr size_t F_RFLAG = F_HFLAG + 512*1024;
static constexpr size_t F_RBEST = F_RFLAG + 16384;
static constexpr size_t F_CNT   = F_RBEST + 16384;
static constexpr size_t F_PREB  = F_CNT  + 256;
static constexpr size_t WS_FULL = F_PREB + 2*MB;

// ---------------- helpers ----------------
__device__ __forceinline__ void gload16(const void* g, void* l) {
    __builtin_amdgcn_global_load_lds(
        (const __attribute__((address_space(1))) void*)g,
        (__attribute__((address_space(3))) void*)l, 16, 0, 0);
}

__device__ __forceinline__ void split1(float x, unsigned short& hi, unsigned short& lo) {
    unsigned u = __float_as_uint(x);
    unsigned r = u + 0x7FFFu + ((u >> 16) & 1u);      // RN-even f32->bf16
    hi = (unsigned short)(r >> 16);
    float rem = x - __uint_as_float(r & 0xFFFF0000u); // exact (Sterbenz)
    unsigned u2 = __float_as_uint(rem);
    unsigned r2 = u2 + 0x7FFFu + ((u2 >> 16) & 1u);
    lo = (unsigned short)(r2 >> 16);
}

__device__ __forceinline__ void merge3(float& b, unsigned& ix, float& s,
                                       float b2, unsigned i2, float s2) {
    if (b2 > b || (b2 == b && i2 < ix)) { s = fmaxf(b, s2); b = b2; ix = i2; }
    else                                { s = fmaxf(s, b2); }
}

// ---------------- prep kernels ----------------
// fused transpose+split for W, Bm, Am (one launch; proven body, block-decode)
__global__ __launch_bounds__(256) void transpose_split_all(
    const float* __restrict__ W, const float* __restrict__ Bm, const float* __restrict__ Am,
    unsigned short* __restrict__ WT0, unsigned short* __restrict__ WT1,
    unsigned short* __restrict__ BmT0, unsigned short* __restrict__ BmT1,
    unsigned short* __restrict__ AT0, unsigned short* __restrict__ AT1) {
    __shared__ float tile[32][33];
    int blk = blockIdx.x;
    const float* src; unsigned short *d0, *d1; int R, C, bx, by;
    if (blk < 4096)      { src = W;  d0 = WT0;  d1 = WT1;  R = 1024; C = 4096; bx = blk & 127; by = blk >> 7; }
    else if (blk < 6144) { src = Bm; d0 = BmT0; d1 = BmT1; R = 512;  C = 4096; blk -= 4096; bx = blk & 127; by = blk >> 7; }
    else                 { src = Am; d0 = AT0;  d1 = AT1;  R = 512;  C = 1024; blk -= 6144; bx = blk & 31;  by = blk >> 5; }
    const int c0 = bx * 32, r0 = by * 32;
    const int tx = threadIdx.x & 31, ty = threadIdx.x >> 5;
#pragma unroll
    for (int e = 0; e < 4; ++e)
        tile[ty + e * 8][tx] = src[(size_t)(r0 + ty + e * 8) * C + c0 + tx];
    __syncthreads();
#pragma unroll
    for (int e = 0; e < 4; ++e) {
        int c = c0 + ty + e * 8;
        unsigned short hi, lo;
        split1(tile[tx][ty + e * 8], hi, lo);
        d0[(size_t)c * R + r0 + tx] = hi;
        d1[(size_t)c * R + r0 + tx] = lo;
    }
}

// fused elementwise split for vd and cd + counter zeroing (one launch)
__global__ __launch_bounds__(256) void split_planes_all(
    const float* __restrict__ vd, const float* __restrict__ cd,
    unsigned short* __restrict__ V0, unsigned short* __restrict__ V1,
    unsigned short* __restrict__ U0, unsigned short* __restrict__ U1,
    unsigned* __restrict__ counters) {
    if (blockIdx.x == 0 && threadIdx.x < 64) counters[threadIdx.x] = 0;
    const int n4v = BATCH * NVIS / 4;                 // 1048576
    const int n4t = n4v + BATCH * NCOND / 4;          // 1572864
    for (int i = blockIdx.x * 256 + threadIdx.x; i < n4t; i += gridDim.x * 256) {
        const float4 v = (i < n4v) ? ((const float4*)vd)[i] : ((const float4*)cd)[i - n4v];
        unsigned short h0,h1,h2,h3,l0,l1,l2,l3;
        split1(v.x,h0,l0); split1(v.y,h1,l1); split1(v.z,h2,l2); split1(v.w,h3,l3);
        if (i < n4v) {
            ((ushort4*)V0)[i] = make_ushort4(h0,h1,h2,h3);
            ((ushort4*)V1)[i] = make_ushort4(l0,l1,l2,l3);
        } else {
            ((ushort4*)U0)[i - n4v] = make_ushort4(h0,h1,h2,h3);
            ((ushort4*)U1)[i - n4v] = make_ushort4(l0,l1,l2,l3);
        }
    }
}

// fused f32 transposes: W->WTf, Bm->BmTf, Am->ATf (after k1; proven)
__global__ __launch_bounds__(256) void transpose_f32_all(
    const float* __restrict__ W, const float* __restrict__ Bm, const float* __restrict__ Am,
    float* __restrict__ WTf, float* __restrict__ BmTf, float* __restrict__ ATf) {
    __shared__ float tile[32][33];
    int blk = blockIdx.x;
    const float* src; float* dst; int R, C, bx, by;
    if (blk < 4096)      { src = W;  dst = WTf;  R = 1024; C = 4096; bx = blk & 127; by = blk >> 7; }
    else if (blk < 6144) { src = Bm; dst = BmTf; R = 512;  C = 4096; blk -= 4096; bx = blk & 127; by = blk >> 7; }
    else                 { src = Am; dst = ATf;  R = 512;  C = 1024; blk -= 6144; bx = blk & 31;  by = blk >> 5; }
    const int c0 = bx * 32, r0 = by * 32;
    const int tx = threadIdx.x & 31, ty = threadIdx.x >> 5;
#pragma unroll
    for (int e = 0; e < 4; ++e)
        tile[ty + e * 8][tx] = src[(size_t)(r0 + ty + e * 8) * C + c0 + tx];
    __syncthreads();
#pragma unroll
    for (int e = 0; e < 4; ++e)
        dst[(size_t)(c0 + ty + e * 8) * R + r0 + tx] = tile[tx][ty + e * 8];
}

// W rows -> 15-bit fixed point (2 i8 planes + per-row inverse scale)
__global__ __launch_bounds__(256) void quantize_w(
    const float* __restrict__ W, signed char* __restrict__ QH,
    signed char* __restrict__ QL, float* __restrict__ SINV) {
    __shared__ float red[256];
    const int i = blockIdx.x, t = threadIdx.x;
    const float* row = W + (size_t)i * NHID;
    float4 v[4];
    float mx = 0.f;
#pragma unroll
    for (int e = 0; e < 4; ++e) {
        v[e] = *(const float4*)(row + e * 1024 + t * 4);
        mx = fmaxf(mx, fmaxf(fmaxf(fabsf(v[e].x), fabsf(v[e].y)),
                             fmaxf(fabsf(v[e].z), fabsf(v[e].w))));
    }
    red[t] = mx; __syncthreads();
    for (int s = 128; s; s >>= 1) {
        if (t < s) red[t] = fmaxf(red[t], red[t + s]);
        __syncthreads();
    }
    const float rm = fmaxf(red[0], 1e-30f);
    const float sc = 32256.f / rm;
    if (t == 0) SINV[i] = rm / 32256.f;
#pragma unroll
    for (int e = 0; e < 4; ++e) {
        const float* pv = (const float*)&v[e];
        unsigned ph = 0, pl = 0;
#pragma unroll
        for (int j = 0; j < 4; ++j) {
            int wq = (int)lrintf(pv[j] * sc);
            int hi = (wq + 128) >> 8;
            int lo = wq - (hi << 8);
            ph |= ((unsigned)hi & 0xFFu) << (8 * j);
            pl |= ((unsigned)lo & 0xFFu) << (8 * j);
        }
        *(unsigned*)(QH + (size_t)i * NHID + e * 1024 + t * 4) = ph;
        *(unsigned*)(QL + (size_t)i * NHID + e * 1024 + t * 4) = pl;
    }
}

// ===========================================================================
// k1_b64: round-12 kernel VERBATIM (best k1 measured: 233us).
// ===========================================================================
__global__ __launch_bounds__(512, 1) void k1_b64(
    const float* __restrict__ noise,
    const unsigned short* __restrict__ V0, const unsigned short* __restrict__ V1,
    const unsigned short* __restrict__ U0, const unsigned short* __restrict__ U1,
    const unsigned short* __restrict__ WT0, const unsigned short* __restrict__ WT1,
    const unsigned short* __restrict__ BmT0, const unsigned short* __restrict__ BmT1,
    const float* __restrict__ cvec, unsigned char* __restrict__ hout,
    unsigned* __restrict__ hcnt, unsigned* __restrict__ hflag)
{
    __shared__ __align__(16) unsigned short As0[256][64], As1[256][64],
                                            Bs0[256][64], Bs1[256][64];
    const int t = threadIdx.x, lane = t & 63, wid = t >> 6;
    const int g = lane >> 4, cc = lane & 15;
    const int wrow = wid >> 2, wcol = wid & 3;      // 2M x 4N waves
    const int nwg = gridDim.x * gridDim.y;
    const int bid = blockIdx.y * gridDim.x + blockIdx.x;
    const int q = nwg >> 3;
    const int swz = (bid & 7) * q + (bid >> 3);
    const int b0 = (swz / gridDim.x) * 256;
    const int j0 = (swz % gridDim.x) * 256;

    f32x4 acc[8][4] = {};
    bf16x8 a0q[4], a1q[4];
    bf16x8 b0a[2][2], b1a[2][2];

    auto lba = [&](int r, int kk) {
        return (size_t)r * 128 + (size_t)(((kk << 2) | g) ^ (r & 7)) * 16;
    };
    auto readA = [&](int mh, int kk) {
#pragma unroll
        for (int k = 0; k < 4; ++k) {
            int r = wrow * 128 + (4 * mh + k) * 16 + cc;
            a0q[k] = *(const bf16x8*)((const char*)As0 + lba(r, kk));
            a1q[k] = *(const bf16x8*)((const char*)As1 + lba(r, kk));
        }
    };
    auto readB = [&](int nh, int kk) {
#pragma unroll
        for (int k = 0; k < 2; ++k) {
            int n = wcol * 64 + (2 * nh + k) * 16 + cc;
            b0a[nh][k] = *(const bf16x8*)((const char*)Bs0 + lba(n, kk));
            b1a[nh][k] = *(const bf16x8*)((const char*)Bs1 + lba(n, kk));
        }
    };
    auto mfma24 = [&](int mh, int nh) {
#pragma unroll
        for (int k = 0; k < 4; ++k)
#pragma unroll
            for (int n = 0; n < 2; ++n) {
                f32x4 c = acc[4 * mh + k][2 * nh + n];
                c = __builtin_amdgcn_mfma_f32_16x16x32_bf16(a0q[k], b0a[nh][n], c, 0, 0, 0);
                c = __builtin_amdgcn_mfma_f32_16x16x32_bf16(a0q[k], b1a[nh][n], c, 0, 0, 0);
                c = __builtin_amdgcn_mfma_f32_16x16x32_bf16(a1q[k], b0a[nh][n], c, 0, 0, 0);
                acc[4 * mh + k][2 * nh + n] = c;
            }
    };

    for (int tt = 0; tt < 24; ++tt) {
        const unsigned short *A0_, *A1_, *B0_, *B1_; int K_, k0_;
        if (tt < 16) { A0_ = V0; A1_ = V1; B0_ = WT0; B1_ = WT1; K_ = 1024; k0_ = tt * 64; }
        else         { A0_ = U0; A1_ = U1; B0_ = BmT0; B1_ = BmT1; K_ = 512; k0_ = (tt - 16) * 64; }
        __syncthreads();   // WAR: previous step's reads done before overwrite
#pragma unroll
        for (int e = 0; e < 4; ++e) {
            int idx = t + e * 512;
            int r = idx >> 3, p = idx & 7;
            int s = p ^ (r & 7);            // pre-swizzled source chunk
            size_t ga = (size_t)(b0 + r) * K_ + k0_ + s * 8;
            size_t gb = (size_t)(j0 + r) * K_ + k0_ + s * 8;
            size_t ldd = (size_t)idx * 16;  // bytes
            gload16(A0_ + ga, (char*)As0 + ldd);
            gload16(A1_ + ga, (char*)As1 + ldd);
            gload16(B0_ + gb, (char*)Bs0 + ldd);
            gload16(B1_ + gb, (char*)Bs1 + ldd);
        }
        __syncthreads();   // drains vmcnt: tile visible
#pragma unroll
        for (int kk = 0; kk < 2; ++kk) {
            readA(0, kk); readB(0, kk);
            __builtin_amdgcn_s_setprio(1); mfma24(0, 0); __builtin_amdgcn_s_setprio(0);
            readB(1, kk);
            __builtin_amdgcn_s_setprio(1); mfma24(0, 1); __builtin_amdgcn_s_setprio(0);
            readA(1, kk);
            __builtin_amdgcn_s_setprio(1); mfma24(1, 0); mfma24(1, 1); __builtin_amdgcn_s_setprio(0);
        }
    }

#pragma unroll
    for (int ni = 0; ni < 4; ++ni) {
        int j = j0 + wcol * 64 + ni * 16 + cc;
        float cj = cvec[j];
#pragma unroll
        for (int mi = 0; mi < 8; ++mi) {
#pragma unroll
            for (int i = 0; i < 4; ++i) {
                int b = b0 + wrow * 128 + mi * 16 + g * 4 + i;
                float z = acc[mi][ni][i] + cj;
                float m = 1.0f / (1.0f + __expf(-z));
                float nv = noise[(size_t)b * NHID + j];
                hout[(size_t)b * NHID + j] = (nv < m) ? (unsigned char)1 : (unsigned char)0;
                if (fabsf(nv - m) < 2.5e-4f) {
                    unsigned p = atomicAdd(hcnt, 1u);
                    if (p < HCAP) hflag[p] = ((unsigned)b << 12) | (unsigned)j;
                }
            }
        }
    }
}

// ===========================================================================
// k2_i8: (round-11/12 kernel, unchanged)
// ===========================================================================
__global__ __launch_bounds__(512, 2) void k2_i8(
    const unsigned char* __restrict__ hbf,
    const unsigned short* __restrict__ U0, const unsigned short* __restrict__ U1,
    const signed char* __restrict__ QH, const signed char* __restrict__ QL,
    const float* __restrict__ SINV,
    const unsigned short* __restrict__ AT0, const unsigned short* __restrict__ AT1,
    const float* __restrict__ bvec, float4* __restrict__ blockbest)
{
    __shared__ __align__(16) char smem[32768];
    __shared__ float4 mbuf[4][128];
    const int t = threadIdx.x, lane = t & 63, wid = t >> 6;
    const int g = lane >> 4, cc = lane & 15;
    const int wrow = wid >> 2, wcol = wid & 3;
    const int pcb = (g ^ ((cc >> 1) & 3)) * 16;
    const int nwg = gridDim.x * gridDim.y;
    const int bid = blockIdx.y * gridDim.x + blockIdx.x;
    const int q = nwg >> 3;
    const int swz = (bid & 7) * q + (bid >> 3);
    const int b0 = (swz / gridDim.x) * 128;
    const int i0 = (swz % gridDim.x) * 128;

    char* Ah  = smem;
    char* Qhs = smem + 8192;
    char* Qls = smem + 16384;

    i32x4 ah[4][2] = {}, al[4][2] = {};

    for (int k0 = 0; k0 < NHID; k0 += 64) {
        __syncthreads();
        {
            int r = t >> 2, s = t & 3, sc = s ^ ((r >> 1) & 3);
            size_t off = (size_t)r * 64 + s * 16;
            gload16(hbf + (size_t)(b0 + r) * NHID + k0 + sc * 16, Ah + off);
            gload16(QH + (size_t)(i0 + r) * NHID + k0 + sc * 16, Qhs + off);
            gload16(QL + (size_t)(i0 + r) * NHID + k0 + sc * 16, Qls + off);
        }
        __syncthreads();
        i32x4 bh[2], bl[2];
#pragma unroll
        for (int ni = 0; ni < 2; ++ni) {
            int n = wcol * 32 + ni * 16 + cc;
            bh[ni] = *(const i32x4*)(Qhs + (size_t)n * 64 + pcb);
            bl[ni] = *(const i32x4*)(Qls + (size_t)n * 64 + pcb);
        }
#pragma unroll
        for (int mi = 0; mi < 4; ++mi) {
            i32x4 a = *(const i32x4*)(Ah + (size_t)(wrow * 64 + mi * 16 + cc) * 64 + pcb);
#pragma unroll
            for (int ni = 0; ni < 2; ++ni) {
                ah[mi][ni] = __builtin_amdgcn_mfma_i32_16x16x64_i8(a, bh[ni], ah[mi][ni], 0, 0, 0);
                al[mi][ni] = __builtin_amdgcn_mfma_i32_16x16x64_i8(a, bl[ni], al[mi][ni], 0, 0, 0);
            }
        }
    }
    f32x4 acc[4][2];
#pragma unroll
    for (int ni = 0; ni < 2; ++ni) {
        int col = i0 + wcol * 32 + ni * 16 + cc;
        float sv = SINV[col];
#pragma unroll
        for (int mi = 0; mi < 4; ++mi)
#pragma unroll
            for (int e = 0; e < 4; ++e)
                acc[mi][ni][e] = fmaf(256.f, (float)ah[mi][ni][e], (float)al[mi][ni][e]) * sv;
    }

    char* As0 = smem;
    char* As1 = smem + 8192;
    char* Bs0 = smem + 16384;
    char* Bs1 = smem + 24576;
    for (int k0 = 0; k0 < NCOND; k0 += 32) {
        __syncthreads();
        {
            int r = t >> 2, s = t & 3, sc = s ^ ((r >> 1) & 3);
            size_t off = (size_t)r * 64 + s * 16;
            size_t ga = (size_t)(b0 + r) * NCOND + k0 + sc * 8;
            gload16(U0 + ga, As0 + off);
            gload16(U1 + ga, As1 + off);
            size_t go = (size_t)(i0 + r) * NCOND + k0 + sc * 8;
            gload16(AT0 + go, Bs0 + off);
            gload16(AT1 + go, Bs1 + off);
        }
        __syncthreads();
        bf16x8 bb0[2], bb1[2];
#pragma unroll
        for (int ni = 0; ni < 2; ++ni) {
            int n = wcol * 32 + ni * 16 + cc;
            bb0[ni] = *(const bf16x8*)(Bs0 + (size_t)n * 64 + pcb);
            bb1[ni] = *(const bf16x8*)(Bs1 + (size_t)n * 64 + pcb);
        }
#pragma unroll
        for (int mi = 0; mi < 4; ++mi) {
            int r = wrow * 64 + mi * 16 + cc;
            bf16x8 a0 = *(const bf16x8*)(As0 + (size_t)r * 64 + pcb);
            bf16x8 a1 = *(const bf16x8*)(As1 + (size_t)r * 64 + pcb);
#pragma unroll
            for (int ni = 0; ni < 2; ++ni) {
                acc[mi][ni] = __builtin_amdgcn_mfma_f32_16x16x32_bf16(a0, bb0[ni], acc[mi][ni], 0, 0, 0);
                acc[mi][ni] = __builtin_amdgcn_mfma_f32_16x16x32_bf16(a0, bb1[ni], acc[mi][ni], 0, 0, 0);
                acc[mi][ni] = __builtin_amdgcn_mfma_f32_16x16x32_bf16(a1, bb0[ni], acc[mi][ni], 0, 0, 0);
            }
        }
    }

#pragma unroll
    for (int ni = 0; ni < 2; ++ni) {
        int colb = i0 + wcol * 32 + ni * 16 + cc;
        float bb = bvec[colb];
#pragma unroll
        for (int mi = 0; mi < 4; ++mi)
#pragma unroll
            for (int i = 0; i < 4; ++i) acc[mi][ni][i] += bb;
    }
#pragma unroll
    for (int mi = 0; mi < 4; ++mi) {
#pragma unroll
        for (int i = 0; i < 4; ++i) {
            float best = acc[mi][0][i];
            unsigned bidx = (unsigned)(i0 + wcol * 32 + cc);
            float sec = -3.4e38f;
            merge3(best, bidx, sec, acc[mi][1][i],
                   (unsigned)(i0 + wcol * 32 + 16 + cc), -3.4e38f);
#pragma unroll
            for (int m = 1; m < 16; m <<= 1) {
                float ob = __shfl_xor(best, m);
                unsigned oi = __shfl_xor(bidx, m);
                float os = __shfl_xor(sec, m);
                merge3(best, bidx, sec, ob, oi, os);
            }
            if (cc == 0)
                mbuf[wcol][wrow * 64 + mi * 16 + g * 4 + i] =
                    make_float4(best, sec, __uint_as_float(bidx), 0.f);
        }
    }
    __syncthreads();
    if (t < 128) {
        float4 f0 = mbuf[0][t];
        float best = f0.x, sec = f0.y;
        unsigned bidx = __float_as_uint(f0.z);
#pragma unroll
        for (int wq = 1; wq < 4; ++wq) {
            float4 fq = mbuf[wq][t];
            merge3(best, bidx, sec, fq.x, __float_as_uint(fq.z), fq.y);
        }
        blockbest[(size_t)(b0 + t) * 8 + (unsigned)(i0 >> 7)] =
            make_float4(best, sec, __uint_as_float(bidx), 0.f);
    }
}

// ---------------- k5: exact f64 recheck, coalesced (h u8) -------------------
__global__ __launch_bounds__(256) void k5_recheck_h(
    const float* __restrict__ vd, const float* __restrict__ cd, const float* __restrict__ noise,
    const float* __restrict__ WTf, const float* __restrict__ BmTf, const float* __restrict__ cvec,
    const unsigned* __restrict__ hcnt, const unsigned* __restrict__ hflag,
    unsigned char* __restrict__ h) {
    const int gw = (blockIdx.x * 256 + threadIdx.x) >> 6, lane = threadIdx.x & 63;
    const int nw = gridDim.x * 4;
    unsigned n = *hcnt; if (n > HCAP) n = HCAP;
    for (unsigned e = gw; e < n; e += nw) {
        unsigned p = hflag[e];
        int b = p >> 12, j = p & 4095;
        double s = 0.0;
        for (int k = lane; k < NVIS; k += 64)
            s += (double)vd[(size_t)b * NVIS + k] * (double)WTf[(size_t)j * NVIS + k];
        for (int k = lane; k < NCOND; k += 64)
            s += (double)cd[(size_t)b * NCOND + k] * (double)BmTf[(size_t)j * NCOND + k];
        for (int m = 32; m; m >>= 1) s += __shfl_xor(s, m);
        if (lane == 0) {
            double z = s + (double)cvec[j];
            double mm = 1.0 / (1.0 + exp(-z));
            h[(size_t)b * NHID + j] =
                ((double)noise[(size_t)b * NHID + j] < mm) ? (unsigned char)1 : (unsigned char)0;
        }
    }
}

// ---------------- k3: merge 8 block-top2 per row; flag near-ties; FUSED
// one-hot write (after butterfly all 8 lanes hold the final idx) ------------
__global__ __launch_bounds__(256) void k3_merge8_onehot(
    const float4* __restrict__ blockbest, unsigned* __restrict__ rowbest,
    unsigned* __restrict__ rcnt, unsigned* __restrict__ rowflag,
    float* __restrict__ out) {
    const int t = threadIdx.x;
    const int row = blockIdx.x * 32 + (t >> 3), e = t & 7;
    float4 f = blockbest[(size_t)row * 8 + e];
    float best = f.x, sec = f.y;
    unsigned idx = __float_as_uint(f.z);
#pragma unroll
    for (int m = 1; m < 8; m <<= 1) {
        float ob = __shfl_xor(best, m);
        unsigned oi = __shfl_xor(idx, m);
        float os = __shfl_xor(sec, m);
        merge3(best, idx, sec, ob, oi, os);
    }
    if (e == 0) {
        rowbest[row] = idx;
        if (best - sec < 4e-3f) {
            unsigned p = atomicAdd(rcnt, 1u);
            if (p < 4096) rowflag[p] = (unsigned)row;
        }
    }
    // fused one-hot: each of the 8 lanes writes 128 floats of its row
    float* orow = out + (size_t)row * NVIS + e * 128;
#pragma unroll
    for (int c = 0; c < 32; ++c) {
        int base = e * 128 + c * 4;
        float4 o;
        o.x = (base + 0 == (int)idx) ? 1.f : 0.f;
        o.y = (base + 1 == (int)idx) ? 1.f : 0.f;
        o.z = (base + 2 == (int)idx) ? 1.f : 0.f;
        o.w = (base + 3 == (int)idx) ? 1.f : 0.f;
        *(float4*)(orow + c * 4) = o;
    }
}

// ---------------- k6a: exact f64 pre for flagged rows (h u8) ---------------
__global__ __launch_bounds__(256) void k6_rows_pre(
    const unsigned char* __restrict__ h, const float* __restrict__ cd,
    const float* __restrict__ W, const float* __restrict__ ATf, const float* __restrict__ bvec,
    const unsigned* __restrict__ rcnt, const unsigned* __restrict__ rowflag,
    double* __restrict__ prebuf) {
    const int gw = (blockIdx.x * 256 + threadIdx.x) >> 6, lane = threadIdx.x & 63;
    const int nw = gridDim.x * 4;
    unsigned n = *rcnt; if (n > RCAP) n = RCAP;
    for (unsigned e = gw; e < n * 1024u; e += nw) {
        int ri = e >> 10, i = e & 1023;
        int b = (int)rowflag[ri];
        double s = 0.0;
        for (int k = lane; k < NHID; k += 64) {
            double hv = h[(size_t)b * NHID + k] ? 1.0 : 0.0;
            s += hv * (double)W[(size_t)i * NHID + k];
        }
        for (int k = lane; k < NCOND; k += 64)
            s += (double)cd[(size_t)b * NCOND + k] * (double)ATf[(size_t)i * NCOND + k];
        for (int m = 32; m; m >>= 1) s += __shfl_xor(s, m);
        if (lane == 0) prebuf[(size_t)ri * 1024 + i] = s + (double)bvec[i];
    }
}

// ---------------- k6b: exact argmax + rewrite flagged rows -----------------
__global__ __launch_bounds__(256) void k6_rows_argmax(
    const unsigned* __restrict__ rcnt, const unsigned* __restrict__ rowflag,
    const double* __restrict__ prebuf, float* __restrict__ out) {
    __shared__ double sv[256];
    __shared__ int si[256];
    unsigned n = *rcnt; if (n > RCAP) n = RCAP;
    const int t = threadIdx.x;
    for (unsigned ri = blockIdx.x; ri < n; ri += gridDim.x) {
        const int row = (int)rowflag[ri];
        const double* pr = prebuf + (size_t)ri * 1024;
        double best = pr[t * 4];
        int bi = t * 4;
#pragma unroll
        for (int e = 1; e < 4; ++e) {
            double v = pr[t * 4 + e];
            if (v > best) { best = v; bi = t * 4 + e; }
        }
        sv[t] = best; si[t] = bi;
        __syncthreads();
        for (int s = 128; s; s >>= 1) {
            if (t < s) {
                double v2 = sv[t + s]; int i2 = si[t + s];
                if (v2 > sv[t] || (v2 == sv[t] && i2 < si[t])) { sv[t] = v2; si[t] = i2; }
            }
            __syncthreads();
        }
        const int amax = si[0];
        const int base = t * 4;
        float4 o;
        o.x = (base + 0 == amax) ? 1.f : 0.f;
        o.y = (base + 1 == amax) ? 1.f : 0.f;
        o.z = (base + 2 == amax) ? 1.f : 0.f;
        o.w = (base + 3 == amax) ? 1.f : 0.f;
        *(float4*)(out + (size_t)row * NVIS + base) = o;
        __syncthreads();
    }
}

// ---------------- launch ----------------
extern "C" void kernel_launch(void* const* d_in, const int* in_sizes, int n_in,
                              void* d_out, int out_size, void* d_ws, size_t ws_size,
                              hipStream_t stream) {
    const float* vd = (const float*)d_in[0];  // [4096,1024]
    const float* cd = (const float*)d_in[1];  // [4096,512]
    const float* nz = (const float*)d_in[2];  // [4096,4096]
    const float* W  = (const float*)d_in[3];  // [1024,4096]
    const float* bv = (const float*)d_in[4];  // [1024]
    const float* cv = (const float*)d_in[5];  // [4096]
    const float* Am = (const float*)d_in[6];  // [512,1024]
    const float* Bm = (const float*)d_in[7];  // [512,4096]
    float* out = (float*)d_out;
    char* w = (char*)d_ws;

    unsigned short* WT0  = (unsigned short*)(w + F_WT0);
    unsigned short* WT1  = (unsigned short*)(w + F_WT1);
    unsigned short* BmT0 = (unsigned short*)(w + F_BMT0);
    unsigned short* BmT1 = (unsigned short*)(w + F_BMT1);
    unsigned short* AT0  = (unsigned short*)(w + F_AT0);
    unsigned short* AT1  = (unsigned short*)(w + F_AT1);
    unsigned short* V0   = (unsigned short*)(w + F_V0);
    unsigned short* V1   = (unsigned short*)(w + F_V1);
    unsigned short* U0   = (unsigned short*)(w + F_U0);
    unsigned short* U1   = (unsigned short*)(w + F_U1);
    signed char*    QH   = (signed char*)(w + F_QH);
    signed char*    QL   = (signed char*)(w + F_QL);
    float*          SINV = (float*)(w + F_SINV);
    unsigned char*  hbf  = (unsigned char*)(w + F_H);
    float4*   blockbest  = (float4*)(w + F_BB);
    unsigned* hflag      = (unsigned*)(w + F_HFLAG);
    unsigned* rowflag    = (unsigned*)(w + F_RFLAG);
    unsigned* rowbest    = (unsigned*)(w + F_RBEST);
    unsigned* counters   = (unsigned*)(w + F_CNT);
    double*   prebuf     = (double*)(w + F_PREB);
    unsigned* hcnt = &counters[0];
    unsigned* rcnt = &counters[1];
    float* WTf32  = (float*)(w + F_V0);    // 16MB (V region, dead after k1)
    float* BmTf32 = (float*)(w + F_WT0);   //  8MB (dead after k1)
    float* ATf32  = (float*)(w + F_WT1);   //  2MB (dead after k1)

    dim3 blk(256);
    transpose_split_all<<<6656, blk, 0, stream>>>(W, Bm, Am, WT0, WT1, BmT0, BmT1, AT0, AT1);
    split_planes_all<<<2048, blk, 0, stream>>>(vd, cd, V0, V1, U0, U1, counters);
    quantize_w<<<NVIS, blk, 0, stream>>>(W, QH, QL, SINV);
    k1_b64<<<dim3(NHID / 256, BATCH / 256), 512, 0, stream>>>(
        nz, V0, V1, U0, U1, WT0, WT1, BmT0, BmT1, cv, hbf, hcnt, hflag);
    transpose_f32_all<<<6656, blk, 0, stream>>>(W, Bm, Am, WTf32, BmTf32, ATf32);
    k5_recheck_h<<<256, blk, 0, stream>>>(vd, cd, nz, WTf32, BmTf32, cv, hcnt, hflag, hbf);
    k2_i8<<<dim3(NVIS / 128, BATCH / 128), 512, 0, stream>>>(
        hbf, U0, U1, QH, QL, SINV, AT0, AT1, bv, blockbest);
    k3_merge8_onehot<<<BATCH / 32, blk, 0, stream>>>(blockbest, rowbest, rcnt, rowflag, out);
    k6_rows_pre<<<512, blk, 0, stream>>>(hbf, cd, W, ATf32, bv, rcnt, rowflag, prebuf);
    k6_rows_argmax<<<64, blk, 0, stream>>>(rcnt, rowflag, prebuf, out);
}